// Round 2
// baseline (3924.712 us; speedup 1.0000x reference)
//
#include <hip/hip_runtime.h>
#include <hip/hip_bf16.h>

// Model constants (fixed by the problem)
#define DLINK 64
#define DNODE 59
#define NGRAPH 256

typedef __hip_bfloat16 bf16;

__device__ __forceinline__ float b2f(bf16 x) { return __bfloat162float(x); }

// Dual-dtype load: isf=1 -> fp32 array, isf=0 -> bf16 array
__device__ __forceinline__ float ldv(const void* p, long long i, int isf) {
    return isf ? ((const float*)p)[i] : b2f(((const bf16*)p)[i]);
}

__device__ __forceinline__ float selu_f(float x) {
    const float scale = 1.0507009873554805f;
    const float alpha = 1.6732632423543772f;
    return x > 0.f ? scale * x : scale * alpha * (__expf(x) - 1.f);
}

__device__ __forceinline__ float sigmoid_f(float x) {
    return 1.f / (1.f + __expf(-x));
}

__device__ __forceinline__ float tanh_f(float x) {
    float t = __expf(-2.f * fabsf(x));
    float r = (1.f - t) / (1.f + t);
    return copysignf(r, x);
}

// ---------------- dtype detector -------------------------------------------------
// Read graph_state as raw 16-bit halves. If the tensor is bf16 (values ~N(0,1)),
// every half has exponent <= 0x81. If it is fp32, the low half of each word is
// mantissa garbage: ~44% of those halves have exponent >= 0x8F. flag=1 => fp32.
__global__ void k_detect(const unsigned short* __restrict__ gsu, int* __restrict__ flag)
{
    if (threadIdx.x == 0 && blockIdx.x == 0) {
        int wild = 0;
        for (int i = 0; i < 512; ++i) {
            int e = (gsu[i] >> 7) & 0xFF;
            if (e >= 0x8F) wild++;
        }
        *flag = (wild >= 20) ? 1 : 0;
    }
}

// ---------------- init: inputs -> fp32 states (node padded to stride 64) ---------
__global__ void k_init(const void* __restrict__ gs, const void* __restrict__ nsb,
                       float* __restrict__ ls, float* __restrict__ ns, int E,
                       const int* __restrict__ dflag)
{
    int isf = *dflag;
    int i = blockIdx.x * 256 + threadIdx.x;
    if (i >= E * 64) return;
    ls[i] = ldv(gs, i, isf);
    int e = i >> 6, c = i & 63;
    ns[i] = (c < DNODE) ? ldv(nsb, (long long)e * DNODE + c, isf) : 0.f;
}

// ---------------- message: selu(concat(gather) @ W + b), atomic scatter-add ------
// KH = per-source width (64 link, 59 node), NN = output width. State rows stride-64.
template<int KH, int NN>
__launch_bounds__(256)
__global__ void k_msg(const float* __restrict__ state,
                      const int* __restrict__ first, const int* __restrict__ second,
                      const void* __restrict__ W,     // [2*KH][NN]
                      const void* __restrict__ bias,  // [NN]
                      float* __restrict__ agg,        // [E][64], pre-zeroed
                      int M, const int* __restrict__ dflag)
{
    __shared__ float As[64][33];   // [pair][k-chunk]
    __shared__ float Bs[32][64];   // [k-chunk][dim]
    __shared__ float bias_s[64];
    __shared__ int   fi[64], se[64];

    const int isf = *dflag;
    const int t  = threadIdx.x;
    const int tx = t & 15, ty = t >> 4;
    const int m0 = blockIdx.x * 64;

    if (t < 64)       { int m = m0 + t;        fi[t] = (m < M) ? first[m]  : 0; }
    else if (t < 128) { int p = t - 64; int m = m0 + p; se[p] = (m < M) ? second[m] : 0; }
    else if (t < 192) { int c = t - 128;       bias_s[c] = (c < NN) ? ldv(bias, c, isf) : 0.f; }

    float acc[4][4];
    #pragma unroll
    for (int i = 0; i < 4; i++)
        #pragma unroll
        for (int j = 0; j < 4; j++) acc[i][j] = 0.f;

    const int K2 = 2 * KH;
    for (int kc = 0; kc < K2; kc += 32) {
        __syncthreads();
        // stage A (gathered): 64 pairs x 32 k
        #pragma unroll
        for (int r = 0; r < 8; ++r) {
            int id = t + r * 256;           // 0..2047
            int p = id >> 5, kk = id & 31;
            int k = kc + kk;
            float v = 0.f;
            if (k < K2) {
                int row = (k < KH) ? fi[p] : se[p];
                int col = (k < KH) ? k : (k - KH);
                v = state[(long long)row * 64 + col];
            }
            As[p][kk] = v;
        }
        // stage B: 32 k x 64 dims (zero-padded)
        #pragma unroll
        for (int r = 0; r < 8; ++r) {
            int id = t + r * 256;
            int kk = id >> 6, c = id & 63;
            int k = kc + kk;
            Bs[kk][c] = (k < K2 && c < NN) ? ldv(W, (long long)k * NN + c, isf) : 0.f;
        }
        __syncthreads();
        #pragma unroll
        for (int kk = 0; kk < 32; ++kk) {
            float a[4], b[4];
            #pragma unroll
            for (int i = 0; i < 4; i++) a[i] = As[ty * 4 + i][kk];
            #pragma unroll
            for (int j = 0; j < 4; j++) b[j] = Bs[kk][tx * 4 + j];
            #pragma unroll
            for (int i = 0; i < 4; i++)
                #pragma unroll
                for (int j = 0; j < 4; j++)
                    acc[i][j] = fmaf(a[i], b[j], acc[i][j]);
        }
    }

    // epilogue: +bias, selu, scatter-add into agg[second[m]]
    #pragma unroll
    for (int i = 0; i < 4; i++) {
        int p = ty * 4 + i;
        int m = m0 + p;
        if (m >= M) continue;
        int dst = se[p];
        #pragma unroll
        for (int j = 0; j < 4; j++) {
            int c = tx * 4 + j;
            if (c < NN) {
                float v = selu_f(acc[i][j] + bias_s[c]);
                atomicAdd(&agg[(long long)dst * 64 + c], v);
            }
        }
    }
}

// ---------------- fused GRU (Keras reset_after=True): h = GRU(x=agg, h) in place --
template<int DNN>
__launch_bounds__(256)
__global__ void k_gru(const float* __restrict__ x,    // agg [E][64]
                      float* __restrict__ h,          // state [E][64], in place
                      const void* __restrict__ Wx, const void* __restrict__ Wh, // [DNN][3*DNN]
                      const void* __restrict__ bx, const void* __restrict__ bh, // [3*DNN]
                      int E, const int* __restrict__ dflag)
{
    __shared__ float Ax[64][17], Ah[64][17];        // [edge][k-chunk]
    __shared__ float Bx[16][3][64], Bh[16][3][64];  // [k-chunk][gate][dim]
    __shared__ float bxs[3][64], bhs[3][64];

    const int isf = *dflag;
    const int t  = threadIdx.x;
    const int tx = t & 15, ty = t >> 4;
    const int e0 = blockIdx.x * 64;

    if (t < 192) {
        int g = t / 64, d = t & 63;
        bxs[g][d] = (d < DNN) ? ldv(bx, g * DNN + d, isf) : 0.f;
        bhs[g][d] = (d < DNN) ? ldv(bh, g * DNN + d, isf) : 0.f;
    }

    float accx[3][4][4], acch[3][4][4];
    #pragma unroll
    for (int g = 0; g < 3; g++)
        #pragma unroll
        for (int i = 0; i < 4; i++)
            #pragma unroll
            for (int j = 0; j < 4; j++) { accx[g][i][j] = 0.f; acch[g][i][j] = 0.f; }

    for (int kc = 0; kc < 64; kc += 16) {
        __syncthreads();
        // stage A: 64 edges x 16 k (x and h)
        #pragma unroll
        for (int r = 0; r < 4; ++r) {
            int id = t + r * 256;           // 0..1023
            int p = id >> 4, kk = id & 15;
            int e = e0 + p, k = kc + kk;
            bool v = (e < E) && (k < DNN);
            Ax[p][kk] = v ? x[(long long)e * 64 + k] : 0.f;
            Ah[p][kk] = v ? h[(long long)e * 64 + k] : 0.f;
        }
        // stage B: 16 k x 3 gates x 64 dims
        #pragma unroll
        for (int r = 0; r < 12; ++r) {
            int id = t + r * 256;           // 0..3071
            int kk = id / 192, rem = id % 192;
            int g = rem >> 6, d = rem & 63;
            int k = kc + kk;
            bool v = (k < DNN) && (d < DNN);
            Bx[kk][g][d] = v ? ldv(Wx, (long long)k * (3 * DNN) + g * DNN + d, isf) : 0.f;
            Bh[kk][g][d] = v ? ldv(Wh, (long long)k * (3 * DNN) + g * DNN + d, isf) : 0.f;
        }
        __syncthreads();
        #pragma unroll 4
        for (int kk = 0; kk < 16; ++kk) {
            float ax[4], ah[4];
            #pragma unroll
            for (int i = 0; i < 4; i++) { ax[i] = Ax[ty * 4 + i][kk]; ah[i] = Ah[ty * 4 + i][kk]; }
            #pragma unroll
            for (int g = 0; g < 3; g++) {
                #pragma unroll
                for (int j = 0; j < 4; j++) {
                    float bxv = Bx[kk][g][tx * 4 + j];
                    float bhv = Bh[kk][g][tx * 4 + j];
                    #pragma unroll
                    for (int i = 0; i < 4; i++) {
                        accx[g][i][j] = fmaf(ax[i], bxv, accx[g][i][j]);
                        acch[g][i][j] = fmaf(ah[i], bhv, acch[g][i][j]);
                    }
                }
            }
        }
    }

    // epilogue: gates (order z, r, hh), in-place state update
    #pragma unroll
    for (int i = 0; i < 4; i++) {
        int e = e0 + ty * 4 + i;
        if (e >= E) continue;
        #pragma unroll
        for (int j = 0; j < 4; j++) {
            int d = tx * 4 + j;
            if (d >= DNN) continue;
            float xz = accx[0][i][j] + bxs[0][d];
            float xr = accx[1][i][j] + bxs[1][d];
            float xh = accx[2][i][j] + bxs[2][d];
            float hz = acch[0][i][j] + bhs[0][d];
            float hr = acch[1][i][j] + bhs[1][d];
            float hh = acch[2][i][j] + bhs[2][d];
            float z = sigmoid_f(xz + hz);
            float r = sigmoid_f(xr + hr);
            float c = tanh_f(xh + r * hh);
            float ho = h[(long long)e * 64 + d];
            h[(long long)e * 64 + d] = z * ho + (1.f - z) * c;
        }
    }
}

// ---------------- readout pool --------------------------------------------------
__global__ void k_pool(const float* __restrict__ ls, const float* __restrict__ ns,
                       const int* __restrict__ gid, float* __restrict__ pooled, int E)
{
    long long i = (long long)blockIdx.x * 256 + threadIdx.x;
    if (i >= (long long)E * 128) return;
    int e = (int)(i >> 7), c = (int)(i & 127);
    if (c >= 64 + DNODE) return;
    int g = gid[e];
    float v = (c < 64) ? ls[(long long)e * 64 + c] : ns[(long long)e * 64 + (c - 64)];
    atomicAdd(&pooled[g * 128 + c], v);
}

// ---------------- readout MLP ----------------------------------------------------
__global__ void k_mlp1(const float* __restrict__ pooled, const void* __restrict__ W1,
                       const void* __restrict__ b1, float* __restrict__ h1,
                       const int* __restrict__ dflag)
{
    int isf = *dflag;
    int g = blockIdx.x, j = threadIdx.x;
    float acc = ldv(b1, j, isf);
    for (int k = 0; k < 64 + DNODE; k++)
        acc = fmaf(pooled[g * 128 + k], ldv(W1, k * 256 + j, isf), acc);
    h1[g * 256 + j] = selu_f(acc);
}

__global__ void k_mlp2(const float* __restrict__ h1, const void* __restrict__ W2,
                       const void* __restrict__ b2, float* __restrict__ h2,
                       const int* __restrict__ dflag)
{
    int isf = *dflag;
    int g = blockIdx.x, j = threadIdx.x;
    float acc = ldv(b2, j, isf);
    for (int k = 0; k < 256; k++)
        acc = fmaf(h1[g * 256 + k], ldv(W2, k * 256 + j, isf), acc);
    h2[g * 256 + j] = selu_f(acc);
}

__global__ void k_mlp3(const float* __restrict__ h2, const void* __restrict__ W3,
                       const void* __restrict__ b3, void* __restrict__ out,
                       const int* __restrict__ dflag)
{
    int isf = *dflag;
    int g = threadIdx.x;   // one block of 256
    float acc = ldv(b3, 0, isf);
    for (int k = 0; k < 256; k++)
        acc = fmaf(h2[g * 256 + k], ldv(W3, k, isf), acc);
    if (isf) ((float*)out)[g] = acc;
    else     ((bf16*)out)[g] = __float2bfloat16(acc);
}

extern "C" void kernel_launch(void* const* d_in, const int* in_sizes, int n_in,
                              void* d_out, int out_size, void* d_ws, size_t ws_size,
                              hipStream_t stream)
{
    const void* graph_state = d_in[0];
    const void* node_state  = d_in[1];
    const int*  first   = (const int*)d_in[2];
    const int*  second  = (const int*)d_in[3];
    const int*  gid     = (const int*)d_in[4];
    // d_in[5] = states_num_edges scalar (derived from in_sizes instead)
    const void* W_msg  = d_in[6];
    const void* b_msg  = d_in[7];
    const void* Wx_e   = d_in[8];
    const void* Wh_e   = d_in[9];
    const void* bx_e   = d_in[10];
    const void* bh_e   = d_in[11];
    const void* W_nmsg = d_in[12];
    const void* b_nmsg = d_in[13];
    const void* Wx_n   = d_in[14];
    const void* Wh_n   = d_in[15];
    const void* bx_n   = d_in[16];
    const void* bh_n   = d_in[17];
    const void* W1 = d_in[18];
    const void* b1 = d_in[19];
    const void* W2 = d_in[20];
    const void* b2 = d_in[21];
    const void* W3 = d_in[22];
    const void* b3 = d_in[23];

    const int E = in_sizes[0] / 64;   // 100000
    const int M = in_sizes[2];        // 300000

    // fp32 workspace layout (~77.5 MB)
    float* ls     = (float*)d_ws;
    float* ns     = ls  + (size_t)E * 64;
    float* agg    = ns  + (size_t)E * 64;
    float* pooled = agg + (size_t)E * 64;
    float* h1     = pooled + 256 * 128;
    float* h2     = h1 + 256 * 256;
    int*   dflag  = (int*)(h2 + 256 * 256);

    k_detect<<<1, 64, 0, stream>>>((const unsigned short*)graph_state, dflag);
    k_init<<<(E * 64 + 255) / 256, 256, 0, stream>>>(graph_state, node_state, ls, ns, E, dflag);

    const int mb = (M + 63) / 64;
    const int eb = (E + 63) / 64;

    for (int it = 0; it < 4; ++it) {
        hipMemsetAsync(agg, 0, (size_t)E * 64 * sizeof(float), stream);
        k_msg<64, 64><<<mb, 256, 0, stream>>>(ls, first, second, W_msg, b_msg, agg, M, dflag);
        k_gru<64><<<eb, 256, 0, stream>>>(agg, ls, Wx_e, Wh_e, bx_e, bh_e, E, dflag);
    }
    for (int it = 0; it < 4; ++it) {
        hipMemsetAsync(agg, 0, (size_t)E * 64 * sizeof(float), stream);
        k_msg<59, 59><<<mb, 256, 0, stream>>>(ns, first, second, W_nmsg, b_nmsg, agg, M, dflag);
        k_gru<59><<<eb, 256, 0, stream>>>(agg, ns, Wx_n, Wh_n, bx_n, bh_n, E, dflag);
    }

    hipMemsetAsync(pooled, 0, 256 * 128 * sizeof(float), stream);
    k_pool<<<(int)(((long long)E * 128 + 255) / 256), 256, 0, stream>>>(ls, ns, gid, pooled, E);
    k_mlp1<<<256, 256, 0, stream>>>(pooled, W1, b1, h1, dflag);
    k_mlp2<<<256, 256, 0, stream>>>(h1, W2, b2, h2, dflag);
    k_mlp3<<<1, 256, 0, stream>>>(h2, W3, b3, d_out, dflag);
}

// Round 3
// 3699.478 us; speedup vs baseline: 1.0609x; 1.0609x over previous
//
#include <hip/hip_runtime.h>
#include <hip/hip_bf16.h>

// Model constants (fixed by the problem)
#define DLINK 64
#define DNODE 59
#define NGRAPH 256

typedef __hip_bfloat16 bf16;

__device__ __forceinline__ float b2f(bf16 x) { return __bfloat162float(x); }

// Dual-dtype load: isf=1 -> fp32 array, isf=0 -> bf16 array
__device__ __forceinline__ float ldv(const void* p, long long i, int isf) {
    return isf ? ((const float*)p)[i] : b2f(((const bf16*)p)[i]);
}

__device__ __forceinline__ float selu_f(float x) {
    const float scale = 1.0507009873554805f;
    const float alpha = 1.6732632423543772f;
    return x > 0.f ? scale * x : scale * alpha * (__expf(x) - 1.f);
}

__device__ __forceinline__ float sigmoid_f(float x) {
    return 1.f / (1.f + __expf(-x));
}

__device__ __forceinline__ float tanh_f(float x) {
    float t = __expf(-2.f * fabsf(x));
    float r = (1.f - t) / (1.f + t);
    return copysignf(r, x);
}

// ---------------- dtype detector (kept: it selected correctly in round 2) --------
__global__ void k_detect(const unsigned short* __restrict__ gsu, int* __restrict__ flag)
{
    if (threadIdx.x == 0 && blockIdx.x == 0) {
        int wild = 0;
        for (int i = 0; i < 512; ++i) {
            int e = (gsu[i] >> 7) & 0xFF;
            if (e >= 0x8F) wild++;
        }
        *flag = (wild >= 20) ? 1 : 0;
    }
}

// ---------------- init: inputs -> fp32 states (node padded to stride 64) ---------
__global__ void k_init(const void* __restrict__ gs, const void* __restrict__ nsb,
                       float* __restrict__ ls, float* __restrict__ ns, int E,
                       const int* __restrict__ dflag)
{
    int isf = *dflag;
    int i = blockIdx.x * 256 + threadIdx.x;
    if (i >= E * 64) return;
    ls[i] = ldv(gs, i, isf);
    int e = i >> 6, c = i & 63;
    ns[i] = (c < DNODE) ? ldv(nsb, (long long)e * DNODE + c, isf) : 0.f;
}

// ---------------- message: selu(concat(gather) @ W + b), atomic scatter-add ------
// Uniform padded-K layout: lds k in [0,64) = first-half (src row k if k<KH),
// k in [64,128) = second-half (src row KH + (k-64) if (k-64)<KH). State rows are
// stride-64 with cols >= KH always zero, so gathers need no column guard.
template<int KH, int NN>
__launch_bounds__(256)
__global__ void k_msg(const float* __restrict__ state,
                      const int* __restrict__ first, const int* __restrict__ second,
                      const void* __restrict__ W,     // [2*KH][NN]
                      const void* __restrict__ bias,  // [NN]
                      float* __restrict__ agg,        // [E][64], pre-zeroed
                      int M, const int* __restrict__ dflag)
{
    __shared__ float Ws[128 * 64];     // [k][c], zero-padded     (32 KB)
    __shared__ float As[32][132];      // [kk][pair], 16B-aligned rows (16.9 KB)
    __shared__ float bias_s[64];
    __shared__ int   fi[128], se[128];

    const int isf = *dflag;
    const int t  = threadIdx.x;
    const int m0 = blockIdx.x * 128;

    // stage indices
    if (t < 128) { int m = m0 + t; fi[t] = (m < M) ? first[m] : 0; }
    else         { int p = t - 128; int m = m0 + p; se[p] = (m < M) ? second[m] : 0; }
    // stage bias
    if (t < 64) bias_s[t] = (t < NN) ? ldv(bias, t, isf) : 0.f;
    // stage whole W, remapped to padded layout
    #pragma unroll
    for (int r = 0; r < 32; ++r) {
        int id = t + r * 256;          // 0..8191
        int k = id >> 6, c = id & 63;
        int half = k >> 6, kk = k & 63;
        float v = 0.f;
        if (kk < KH && c < NN)
            v = ldv(W, (long long)(half ? (KH + kk) : kk) * NN + c, isf);
        Ws[k * 64 + c] = v;
    }

    const int ro = t >> 4;   // 0..15 (8 rows each)
    const int co = t & 15;   // 0..15 (4 cols each)

    float acc[8][4];
    #pragma unroll
    for (int i = 0; i < 8; i++)
        #pragma unroll
        for (int j = 0; j < 4; j++) acc[i][j] = 0.f;

    for (int kc = 0; kc < 128; kc += 32) {
        __syncthreads();               // covers staging above on first pass
        // stage A chunk (gathered, float4, k-major transposed)
        #pragma unroll
        for (int r = 0; r < 4; ++r) {
            int id = t + r * 256;      // 0..1023
            int p = id >> 3;           // pair 0..127
            int q = id & 7;            // float4 index within 32 k
            int k = kc + q * 4;        // chunk never straddles the 64-boundary
            int row = (k < 64) ? fi[p] : se[p];
            float4 v = *(const float4*)&state[(long long)row * 64 + (k & 63)];
            As[q * 4 + 0][p] = v.x;
            As[q * 4 + 1][p] = v.y;
            As[q * 4 + 2][p] = v.z;
            As[q * 4 + 3][p] = v.w;
        }
        __syncthreads();
        #pragma unroll
        for (int kk = 0; kk < 32; ++kk) {
            float a[8], b[4];
            *(float4*)&b[0] = *(const float4*)&Ws[(kc + kk) * 64 + co * 4];
            *(float4*)&a[0] = *(const float4*)&As[kk][ro * 8];
            *(float4*)&a[4] = *(const float4*)&As[kk][ro * 8 + 4];
            #pragma unroll
            for (int i = 0; i < 8; i++)
                #pragma unroll
                for (int j = 0; j < 4; j++)
                    acc[i][j] = fmaf(a[i], b[j], acc[i][j]);
        }
    }

    // epilogue: +bias, selu, scatter-add into agg[second[m]]
    #pragma unroll
    for (int i = 0; i < 8; i++) {
        int p = ro * 8 + i;
        int m = m0 + p;
        if (m >= M) continue;
        int dst = se[p];
        #pragma unroll
        for (int j = 0; j < 4; j++) {
            int c = co * 4 + j;
            if (c < NN)
                atomicAdd(&agg[(long long)dst * 64 + c], selu_f(acc[i][j] + bias_s[c]));
        }
    }
}

// ---------------- fused GRU (Keras reset_after=True): h = GRU(x=agg, h) in place --
template<int DNN>
__launch_bounds__(256)
__global__ void k_gru(const float* __restrict__ x,    // agg [E][64]
                      float* __restrict__ h,          // state [E][64], in place
                      const void* __restrict__ Wx, const void* __restrict__ Wh, // [DNN][3*DNN]
                      const void* __restrict__ bx, const void* __restrict__ bh, // [3*DNN]
                      int E, const int* __restrict__ dflag)
{
    __shared__ float Axt[16][68], Aht[16][68];      // [kk][edge], 16B-aligned rows
    __shared__ float Bx[16][3][64], Bh[16][3][64];  // [kk][gate][dim]
    __shared__ float bxs[3][64], bhs[3][64];

    const int isf = *dflag;
    const int t  = threadIdx.x;
    const int tx = t & 15, ty = t >> 4;
    const int e0 = blockIdx.x * 64;

    if (t < 192) {
        int g = t / 64, d = t & 63;
        bxs[g][d] = (d < DNN) ? ldv(bx, g * DNN + d, isf) : 0.f;
        bhs[g][d] = (d < DNN) ? ldv(bh, g * DNN + d, isf) : 0.f;
    }

    float accx[3][4][4], acch[3][4][4];
    #pragma unroll
    for (int g = 0; g < 3; g++)
        #pragma unroll
        for (int i = 0; i < 4; i++)
            #pragma unroll
            for (int j = 0; j < 4; j++) { accx[g][i][j] = 0.f; acch[g][i][j] = 0.f; }

    for (int kc = 0; kc < 64; kc += 16) {
        __syncthreads();
        // stage A (x and h), float4 along k, written k-major. State cols >= DNN are
        // zero in both buffers, so no column guard is needed.
        {
            int e = e0 + (t >> 2);     // 64 edges
            int q = t & 3;             // 4 float4s cover 16 k
            float4 vx = make_float4(0.f, 0.f, 0.f, 0.f), vh = vx;
            if (e < E) {
                vx = *(const float4*)&x[(long long)e * 64 + kc + q * 4];
                vh = *(const float4*)&h[(long long)e * 64 + kc + q * 4];
            }
            int p = t >> 2;
            Axt[q * 4 + 0][p] = vx.x; Axt[q * 4 + 1][p] = vx.y;
            Axt[q * 4 + 2][p] = vx.z; Axt[q * 4 + 3][p] = vx.w;
            Aht[q * 4 + 0][p] = vh.x; Aht[q * 4 + 1][p] = vh.y;
            Aht[q * 4 + 2][p] = vh.z; Aht[q * 4 + 3][p] = vh.w;
        }
        // stage B: 16 k x 3 gates x 64 dims
        #pragma unroll
        for (int r = 0; r < 12; ++r) {
            int id = t + r * 256;           // 0..3071
            int kk = id / 192, rem = id % 192;
            int g = rem >> 6, d = rem & 63;
            int k = kc + kk;
            bool v = (k < DNN) && (d < DNN);
            Bx[kk][g][d] = v ? ldv(Wx, (long long)k * (3 * DNN) + g * DNN + d, isf) : 0.f;
            Bh[kk][g][d] = v ? ldv(Wh, (long long)k * (3 * DNN) + g * DNN + d, isf) : 0.f;
        }
        __syncthreads();
        #pragma unroll 4
        for (int kk = 0; kk < 16; ++kk) {
            float ax[4], ah[4];
            *(float4*)&ax[0] = *(const float4*)&Axt[kk][ty * 4];
            *(float4*)&ah[0] = *(const float4*)&Aht[kk][ty * 4];
            #pragma unroll
            for (int g = 0; g < 3; g++) {
                float bxv[4], bhv[4];
                *(float4*)&bxv[0] = *(const float4*)&Bx[kk][g][tx * 4];
                *(float4*)&bhv[0] = *(const float4*)&Bh[kk][g][tx * 4];
                #pragma unroll
                for (int j = 0; j < 4; j++)
                    #pragma unroll
                    for (int i = 0; i < 4; i++) {
                        accx[g][i][j] = fmaf(ax[i], bxv[j], accx[g][i][j]);
                        acch[g][i][j] = fmaf(ah[i], bhv[j], acch[g][i][j]);
                    }
            }
        }
    }

    // epilogue: gates (order z, r, hh), in-place state update
    #pragma unroll
    for (int i = 0; i < 4; i++) {
        int e = e0 + ty * 4 + i;
        if (e >= E) continue;
        #pragma unroll
        for (int j = 0; j < 4; j++) {
            int d = tx * 4 + j;
            if (d >= DNN) continue;
            float xz = accx[0][i][j] + bxs[0][d];
            float xr = accx[1][i][j] + bxs[1][d];
            float xh = accx[2][i][j] + bxs[2][d];
            float hz = acch[0][i][j] + bhs[0][d];
            float hr = acch[1][i][j] + bhs[1][d];
            float hh = acch[2][i][j] + bhs[2][d];
            float z = sigmoid_f(xz + hz);
            float r = sigmoid_f(xr + hr);
            float c = tanh_f(xh + r * hh);
            float ho = h[(long long)e * 64 + d];
            h[(long long)e * 64 + d] = z * ho + (1.f - z) * c;
        }
    }
}

// ---------------- readout pool (64-way replicated to kill atomic contention) -----
__global__ void k_pool(const float* __restrict__ ls, const float* __restrict__ ns,
                       const int* __restrict__ gid, float* __restrict__ pooledR, int E)
{
    long long i = (long long)blockIdx.x * 256 + threadIdx.x;
    if (i >= (long long)E * 128) return;
    int e = (int)(i >> 7), c = (int)(i & 127);
    if (c >= 64 + DNODE) return;
    int g = gid[e];
    int rep = blockIdx.x & 63;
    float v = (c < 64) ? ls[(long long)e * 64 + c] : ns[(long long)e * 64 + (c - 64)];
    atomicAdd(&pooledR[((long long)rep * NGRAPH + g) * 128 + c], v);
}

__global__ void k_pool_red(const float* __restrict__ pooledR, float* __restrict__ pooled)
{
    int i = blockIdx.x * 256 + threadIdx.x;   // 0..32767
    float s = 0.f;
    for (int r = 0; r < 64; ++r) s += pooledR[(long long)r * NGRAPH * 128 + i];
    pooled[i] = s;
}

// ---------------- readout MLP ----------------------------------------------------
__global__ void k_mlp1(const float* __restrict__ pooled, const void* __restrict__ W1,
                       const void* __restrict__ b1, float* __restrict__ h1,
                       const int* __restrict__ dflag)
{
    int isf = *dflag;
    int g = blockIdx.x, j = threadIdx.x;
    float acc = ldv(b1, j, isf);
    for (int k = 0; k < 64 + DNODE; k++)
        acc = fmaf(pooled[g * 128 + k], ldv(W1, k * 256 + j, isf), acc);
    h1[g * 256 + j] = selu_f(acc);
}

__global__ void k_mlp2(const float* __restrict__ h1, const void* __restrict__ W2,
                       const void* __restrict__ b2, float* __restrict__ h2,
                       const int* __restrict__ dflag)
{
    int isf = *dflag;
    int g = blockIdx.x, j = threadIdx.x;
    float acc = ldv(b2, j, isf);
    for (int k = 0; k < 256; k++)
        acc = fmaf(h1[g * 256 + k], ldv(W2, k * 256 + j, isf), acc);
    h2[g * 256 + j] = selu_f(acc);
}

__global__ void k_mlp3(const float* __restrict__ h2, const void* __restrict__ W3,
                       const void* __restrict__ b3, void* __restrict__ out,
                       const int* __restrict__ dflag)
{
    int isf = *dflag;
    int g = threadIdx.x;   // one block of 256
    float acc = ldv(b3, 0, isf);
    for (int k = 0; k < 256; k++)
        acc = fmaf(h2[g * 256 + k], ldv(W3, k, isf), acc);
    if (isf) ((float*)out)[g] = acc;
    else     ((bf16*)out)[g] = __float2bfloat16(acc);
}

extern "C" void kernel_launch(void* const* d_in, const int* in_sizes, int n_in,
                              void* d_out, int out_size, void* d_ws, size_t ws_size,
                              hipStream_t stream)
{
    const void* graph_state = d_in[0];
    const void* node_state  = d_in[1];
    const int*  first   = (const int*)d_in[2];
    const int*  second  = (const int*)d_in[3];
    const int*  gid     = (const int*)d_in[4];
    const void* W_msg  = d_in[6];
    const void* b_msg  = d_in[7];
    const void* Wx_e   = d_in[8];
    const void* Wh_e   = d_in[9];
    const void* bx_e   = d_in[10];
    const void* bh_e   = d_in[11];
    const void* W_nmsg = d_in[12];
    const void* b_nmsg = d_in[13];
    const void* Wx_n   = d_in[14];
    const void* Wh_n   = d_in[15];
    const void* bx_n   = d_in[16];
    const void* bh_n   = d_in[17];
    const void* W1 = d_in[18];
    const void* b1 = d_in[19];
    const void* W2 = d_in[20];
    const void* b2 = d_in[21];
    const void* W3 = d_in[22];
    const void* b3 = d_in[23];

    const int E = in_sizes[0] / 64;   // 100000
    const int M = in_sizes[2];        // 300000

    // fp32 workspace layout (~77.6 MB)
    float* ls     = (float*)d_ws;
    float* ns     = ls  + (size_t)E * 64;
    float* agg    = ns  + (size_t)E * 64;
    float* pooled = agg + (size_t)E * 64;
    float* h1     = pooled + 256 * 128;
    float* h2     = h1 + 256 * 256;
    int*   dflag  = (int*)(h2 + 256 * 256);
    // after the iteration loops, agg is dead: reuse it for the pool replicas (8.4 MB <= 25.6 MB)
    float* pooledR = agg;

    k_detect<<<1, 64, 0, stream>>>((const unsigned short*)graph_state, dflag);
    k_init<<<(E * 64 + 255) / 256, 256, 0, stream>>>(graph_state, node_state, ls, ns, E, dflag);

    const int mb = (M + 127) / 128;
    const int eb = (E + 63) / 64;

    for (int it = 0; it < 4; ++it) {
        hipMemsetAsync(agg, 0, (size_t)E * 64 * sizeof(float), stream);
        k_msg<64, 64><<<mb, 256, 0, stream>>>(ls, first, second, W_msg, b_msg, agg, M, dflag);
        k_gru<64><<<eb, 256, 0, stream>>>(agg, ls, Wx_e, Wh_e, bx_e, bh_e, E, dflag);
    }
    for (int it = 0; it < 4; ++it) {
        hipMemsetAsync(agg, 0, (size_t)E * 64 * sizeof(float), stream);
        k_msg<59, 59><<<mb, 256, 0, stream>>>(ns, first, second, W_nmsg, b_nmsg, agg, M, dflag);
        k_gru<59><<<eb, 256, 0, stream>>>(agg, ns, Wx_n, Wh_n, bx_n, bh_n, E, dflag);
    }

    hipMemsetAsync(pooledR, 0, (size_t)64 * NGRAPH * 128 * sizeof(float), stream);
    k_pool<<<(int)(((long long)E * 128 + 255) / 256), 256, 0, stream>>>(ls, ns, gid, pooledR, E);
    k_pool_red<<<(NGRAPH * 128) / 256, 256, 0, stream>>>(pooledR, pooled);
    k_mlp1<<<256, 256, 0, stream>>>(pooled, W1, b1, h1, dflag);
    k_mlp2<<<256, 256, 0, stream>>>(h1, W2, b2, h2, dflag);
    k_mlp3<<<1, 256, 0, stream>>>(h2, W3, b3, d_out, dflag);
}

// Round 5
// 1919.719 us; speedup vs baseline: 2.0444x; 1.9271x over previous
//
#include <hip/hip_runtime.h>
#include <hip/hip_bf16.h>

#define DNODE 59
#define NGRAPH 256
typedef __hip_bfloat16 bf16;
typedef long long ll;

__device__ __forceinline__ float b2f(bf16 x) { return __bfloat162float(x); }
__device__ __forceinline__ float ldv(const void* p, ll i, int isf) {
    return isf ? ((const float*)p)[i] : b2f(((const bf16*)p)[i]);
}
__device__ __forceinline__ float selu_f(float x) {
    const float scale = 1.0507009873554805f;
    const float alpha = 1.6732632423543772f;
    return x > 0.f ? scale * x : scale * alpha * (__expf(x) - 1.f);
}
__device__ __forceinline__ float sigmoid_f(float x) { return 1.f / (1.f + __expf(-x)); }
__device__ __forceinline__ float tanh_f(float x) {
    float t = __expf(-2.f * fabsf(x));
    return copysignf((1.f - t) / (1.f + t), x);
}

// ---------------- dtype detector (bf16 vs fp32 tensors) --------------------------
__global__ void k_detect(const unsigned short* __restrict__ gsu, int* __restrict__ flag)
{
    if (threadIdx.x == 0 && blockIdx.x == 0) {
        int wild = 0;
        for (int i = 0; i < 512; ++i) {
            int e = (gsu[i] >> 7) & 0xFF;
            if (e >= 0x8F) wild++;
        }
        *flag = (wild >= 20) ? 1 : 0;
    }
}

// ---------------- init states -> fp32 (node padded to stride 64) -----------------
__global__ void k_init(const void* __restrict__ gs, const void* __restrict__ nsb,
                       float* __restrict__ ls, float* __restrict__ ns, int E,
                       const int* __restrict__ dflag)
{
    int isf = *dflag;
    int i = blockIdx.x * 256 + threadIdx.x;
    if (i >= E * 64) return;
    ls[i] = ldv(gs, i, isf);
    int e = i >> 6, c = i & 63;
    ns[i] = (c < DNODE) ? ldv(nsb, (ll)e * DNODE + c, isf) : 0.f;
}

// ---------------- weight prep (hot-path weights only) ----------------------------
// msg W [2*KH][NN] -> [128][64]: k in [0,64) = first-half rows, [64,128) = second.
__global__ void k_prep_msgW(float* __restrict__ dst, const void* __restrict__ src,
                            int KH, int NN, const int* __restrict__ dflag)
{
    int isf = *dflag;
    int i = blockIdx.x * 256 + threadIdx.x;
    if (i >= 128 * 64) return;
    int k = i >> 6, c = i & 63;
    int half = k >> 6, kk = k & 63;
    float v = 0.f;
    if (kk < KH && c < NN) v = ldv(src, (ll)(half * KH + kk) * NN + c, isf);
    dst[i] = v;
}
// GRU W [D][3*D] -> [64][192] gate-blocked 64
__global__ void k_prep_gruW(float* __restrict__ dst, const void* __restrict__ src,
                            int D, const int* __restrict__ dflag)
{
    int isf = *dflag;
    int i = blockIdx.x * 256 + threadIdx.x;
    if (i >= 64 * 192) return;
    int k = i / 192, rem = i % 192, g = rem >> 6, d = rem & 63;
    float v = 0.f;
    if (k < D && d < D) v = ldv(src, (ll)k * 3 * D + g * D + d, isf);
    dst[i] = v;
}
// GRU bias [3*D] -> [192]
__global__ void k_prep_grub(float* __restrict__ dst, const void* __restrict__ src,
                            int D, const int* __restrict__ dflag)
{
    int t = threadIdx.x;
    if (t >= 192) return;
    int g = t >> 6, d = t & 63;
    dst[t] = (d < D) ? ldv(src, g * D + d, *dflag) : 0.f;
}
// padded vector: dst[i] = i<S ? src[i] : 0
__global__ void k_prep_padvec(float* __restrict__ dst, const void* __restrict__ src,
                              int S, int D, const int* __restrict__ dflag)
{
    int i = blockIdx.x * 256 + threadIdx.x;
    if (i < D) dst[i] = (i < S) ? ldv(src, i, *dflag) : 0.f;
}

// ---------------- counting sort of pairs by `second` ------------------------------
__global__ void k_hist(const int* __restrict__ second, int* __restrict__ cnt, int M)
{
    int m = blockIdx.x * 256 + threadIdx.x;
    if (m < M) atomicAdd(&cnt[second[m]], 1);
}
__global__ void k_scan_block(int* __restrict__ cnt, int* __restrict__ bsum, int E)
{
    __shared__ int s[256];
    int t = threadIdx.x, i = blockIdx.x * 256 + t;
    int v = (i < E) ? cnt[i] : 0;
    s[t] = v;
    __syncthreads();
    #pragma unroll
    for (int d = 1; d < 256; d <<= 1) {
        int xv = (t >= d) ? s[t - d] : 0;
        __syncthreads();
        s[t] += xv;
        __syncthreads();
    }
    if (i < E) cnt[i] = s[t] - v;           // exclusive within block
    if (t == 255) bsum[blockIdx.x] = s[255];
}
__global__ void k_scan_top(const int* __restrict__ bsum, int* __restrict__ ebsum, int NB)
{
    if (threadIdx.x == 0 && blockIdx.x == 0) {
        int run = 0;
        for (int b = 0; b < NB; ++b) { ebsum[b] = run; run += bsum[b]; }
    }
}
__global__ void k_scan_add(int* __restrict__ cnt, const int* __restrict__ ebsum, int E)
{
    int i = blockIdx.x * 256 + threadIdx.x;
    if (i < E) cnt[i] += ebsum[blockIdx.x];
}
__global__ void k_scatter(const int* __restrict__ second, int* __restrict__ cnt,
                          int* __restrict__ perm, int M)
{
    int m = blockIdx.x * 256 + threadIdx.x;
    if (m < M) {
        int s = second[m];
        int pos = atomicAdd(&cnt[s], 1);
        perm[pos] = m;
    }
}

// ---------------- message: sorted pairs, LDS segment-reduce, mostly plain stores --
__launch_bounds__(256)
__global__ void k_msg(const float* __restrict__ state,
                      const int* __restrict__ first, const int* __restrict__ second,
                      const int* __restrict__ perm,
                      const float* __restrict__ Wm,   // [128][64] fp32 padded
                      const float* __restrict__ bm,   // [64] fp32 padded
                      float* __restrict__ agg,        // [E][64], pre-zeroed
                      int M)
{
    __shared__ float Ws[32 * 68];     // W chunk [kk][c] (8.7 KB)
    __shared__ float AsMs[4224];      // As: [32][132] / Ms: [128][33] overlay (16.9 KB)
    __shared__ float bias_s[64];
    __shared__ int fi[128], se[128];

    const int t  = threadIdx.x;
    const int m0 = blockIdx.x * 128;

    if (t < 128) {
        int m = m0 + t;
        if (m < M) { int pm = perm[m]; fi[t] = first[pm]; se[t] = second[pm]; }
        else       { fi[t] = 0; se[t] = -1; }
    } else {
        int c = t - 128;
        if (c < 64) bias_s[c] = bm[c];
    }

    const int ro = t >> 4;   // 0..15: 8 pairs each
    const int co = t & 15;   // 0..15: 4 cols each

    float acc[8][4];
    #pragma unroll
    for (int i = 0; i < 8; i++)
        #pragma unroll
        for (int j = 0; j < 4; j++) acc[i][j] = 0.f;

    for (int kc = 0; kc < 128; kc += 32) {
        __syncthreads();               // covers index/bias staging on first pass
        {   // stage W chunk (coalesced float4 from L2-hot prepped buffer)
            int r0 = t >> 3, c0 = (t & 7) * 8;
            float4 w0 = *(const float4*)&Wm[(kc + r0) * 64 + c0];
            float4 w1 = *(const float4*)&Wm[(kc + r0) * 64 + c0 + 4];
            *(float4*)&Ws[r0 * 68 + c0]     = w0;
            *(float4*)&Ws[r0 * 68 + c0 + 4] = w1;
        }
        // stage A chunk (gathered float4, k-major)
        #pragma unroll
        for (int r = 0; r < 4; ++r) {
            int id = t + r * 256;      // 0..1023
            int p = id >> 3, q = id & 7;
            int k = kc + q * 4;        // chunk never straddles the 64-boundary
            int row = (k < 64) ? fi[p] : se[p];
            if (row < 0) row = 0;
            float4 v = *(const float4*)&state[(ll)row * 64 + (k & 63)];
            AsMs[(q * 4 + 0) * 132 + p] = v.x;
            AsMs[(q * 4 + 1) * 132 + p] = v.y;
            AsMs[(q * 4 + 2) * 132 + p] = v.z;
            AsMs[(q * 4 + 3) * 132 + p] = v.w;
        }
        __syncthreads();
        #pragma unroll
        for (int kk = 0; kk < 32; ++kk) {
            float a[8], b[4];
            *(float4*)&b[0] = *(const float4*)&Ws[kk * 68 + co * 4];
            *(float4*)&a[0] = *(const float4*)&AsMs[kk * 132 + ro * 8];
            *(float4*)&a[4] = *(const float4*)&AsMs[kk * 132 + ro * 8 + 4];
            #pragma unroll
            for (int i = 0; i < 8; i++)
                #pragma unroll
                for (int j = 0; j < 4; j++)
                    acc[i][j] = fmaf(a[i], b[j], acc[i][j]);
        }
    }

    // epilogue: selu, LDS segment-reduce over sorted runs; plain store for interior
    // runs, atomic only at block-boundary runs. Two col-halves reuse AsMs as Ms[128][33].
    #pragma unroll
    for (int hh = 0; hh < 2; ++hh) {
        __syncthreads();
        if ((co >> 3) == hh) {
            int c0 = (co & 7) * 4;
            #pragma unroll
            for (int i = 0; i < 8; i++)
                #pragma unroll
                for (int j = 0; j < 4; j++)
                    AsMs[(ro * 8 + i) * 33 + c0 + j] = selu_f(acc[i][j] + bias_s[co * 4 + j]);
        }
        __syncthreads();
        for (int cell = t; cell < 4096; cell += 256) {
            int p = cell >> 5, c32 = cell & 31;
            int dst = se[p];
            if (dst < 0) continue;
            if (p > 0 && se[p - 1] == dst) continue;   // not a run head
            float s = 0.f;
            int q = p;
            while (q < 128 && se[q] == dst) { s += AsMs[q * 33 + c32]; ++q; }
            int col = hh * 32 + c32;
            if (p == 0 || q == 128) atomicAdd(&agg[(ll)dst * 64 + col], s);
            else                    agg[(ll)dst * 64 + col] = s;
        }
    }
}

// ---------------- fused GRU: h = GRU(x=agg, h) in place, fp32 prepped weights -----
__launch_bounds__(256)
__global__ void k_gru(const float* __restrict__ x, float* __restrict__ h,
                      const float* __restrict__ Gx, const float* __restrict__ Gh, // [64][192]
                      const float* __restrict__ bgx, const float* __restrict__ bgh, // [192]
                      int E)
{
    __shared__ float Axt[16 * 68], Aht[16 * 68];
    __shared__ float BxS[3072], BhS[3072];
    __shared__ float bxs[192], bhs[192];

    const int t = threadIdx.x, tx = t & 15, ty = t >> 4;
    const int e0 = blockIdx.x * 64;

    if (t < 192) { bxs[t] = bgx[t]; bhs[t] = bgh[t]; }

    float accx[3][4][4], acch[3][4][4];
    #pragma unroll
    for (int g = 0; g < 3; g++)
        #pragma unroll
        for (int i = 0; i < 4; i++)
            #pragma unroll
            for (int j = 0; j < 4; j++) { accx[g][i][j] = 0.f; acch[g][i][j] = 0.f; }

    for (int kc = 0; kc < 64; kc += 16) {
        __syncthreads();
        {   // stage A (x and h), float4 along k, k-major
            int p = t >> 2, q = t & 3;
            int e = e0 + p;
            float4 vx = make_float4(0.f, 0.f, 0.f, 0.f), vh = vx;
            if (e < E) {
                vx = *(const float4*)&x[(ll)e * 64 + kc + q * 4];
                vh = *(const float4*)&h[(ll)e * 64 + kc + q * 4];
            }
            Axt[(q * 4 + 0) * 68 + p] = vx.x; Axt[(q * 4 + 1) * 68 + p] = vx.y;
            Axt[(q * 4 + 2) * 68 + p] = vx.z; Axt[(q * 4 + 3) * 68 + p] = vx.w;
            Aht[(q * 4 + 0) * 68 + p] = vh.x; Aht[(q * 4 + 1) * 68 + p] = vh.y;
            Aht[(q * 4 + 2) * 68 + p] = vh.z; Aht[(q * 4 + 3) * 68 + p] = vh.w;
        }
        // stage B chunk: [16][192] of each, coalesced float4
        #pragma unroll
        for (int r = 0; r < 3; ++r) {
            int flat = (t + r * 256) * 4;       // 0..12284
            int kk = flat / 192, rem = flat % 192;
            *(float4*)&BxS[flat] = *(const float4*)&Gx[(kc + kk) * 192 + rem];
            *(float4*)&BhS[flat] = *(const float4*)&Gh[(kc + kk) * 192 + rem];
        }
        __syncthreads();
        #pragma unroll 4
        for (int kk = 0; kk < 16; ++kk) {
            float ax[4], ah[4];
            *(float4*)&ax[0] = *(const float4*)&Axt[kk * 68 + ty * 4];
            *(float4*)&ah[0] = *(const float4*)&Aht[kk * 68 + ty * 4];
            #pragma unroll
            for (int g = 0; g < 3; g++) {
                float bx4[4], bh4[4];
                *(float4*)&bx4[0] = *(const float4*)&BxS[kk * 192 + g * 64 + tx * 4];
                *(float4*)&bh4[0] = *(const float4*)&BhS[kk * 192 + g * 64 + tx * 4];
                #pragma unroll
                for (int j = 0; j < 4; j++)
                    #pragma unroll
                    for (int i = 0; i < 4; i++) {
                        accx[g][i][j] = fmaf(ax[i], bx4[j], accx[g][i][j]);
                        acch[g][i][j] = fmaf(ah[i], bh4[j], acch[g][i][j]);
                    }
            }
        }
    }

    // epilogue: gates (z, r, hh), float4 in-place update
    #pragma unroll
    for (int i = 0; i < 4; i++) {
        int e = e0 + ty * 4 + i;
        if (e >= E) continue;
        float4 ho4 = *(const float4*)&h[(ll)e * 64 + tx * 4];
        float ho[4] = { ho4.x, ho4.y, ho4.z, ho4.w };
        float out[4];
        #pragma unroll
        for (int j = 0; j < 4; j++) {
            int d = tx * 4 + j;
            float z = sigmoid_f(accx[0][i][j] + bxs[d] + acch[0][i][j] + bhs[d]);
            float r = sigmoid_f(accx[1][i][j] + bxs[64 + d] + acch[1][i][j] + bhs[64 + d]);
            float c = tanh_f(accx[2][i][j] + bxs[128 + d] + r * (acch[2][i][j] + bhs[128 + d]));
            out[j] = z * ho[j] + (1.f - z) * c;
        }
        *(float4*)&h[(ll)e * 64 + tx * 4] = make_float4(out[0], out[1], out[2], out[3]);
    }
}

// ---------------- readout pool (64-way replicated atomics) -----------------------
__global__ void k_pool(const float* __restrict__ ls, const float* __restrict__ ns,
                       const int* __restrict__ gid, float* __restrict__ pooledR, int E)
{
    ll i = (ll)blockIdx.x * 256 + threadIdx.x;
    if (i >= (ll)E * 128) return;
    int e = (int)(i >> 7), c = (int)(i & 127);
    if (c >= 64 + DNODE) return;
    int g = gid[e];
    int rep = blockIdx.x & 63;
    float v = (c < 64) ? ls[(ll)e * 64 + c] : ns[(ll)e * 64 + (c - 64)];
    atomicAdd(&pooledR[((ll)rep * NGRAPH + g) * 128 + c], v);
}
__global__ void k_pool_red(const float* __restrict__ pooledR, float* __restrict__ pooled)
{
    int i = blockIdx.x * 256 + threadIdx.x;
    float s = 0.f;
    for (int r = 0; r < 64; ++r) s += pooledR[(ll)r * NGRAPH * 128 + i];
    pooled[i] = s;
}

// ---------------- readout MLP (raw weights via ldv; not a bottleneck) ------------
__global__ void k_mlp1(const float* __restrict__ pooled, const void* __restrict__ W1,
                       const void* __restrict__ b1, float* __restrict__ h1,
                       const int* __restrict__ dflag)
{
    int isf = *dflag;
    int g = blockIdx.x, j = threadIdx.x;
    float acc = ldv(b1, j, isf);
    for (int k = 0; k < 64 + DNODE; k++)
        acc = fmaf(pooled[g * 128 + k], ldv(W1, (ll)k * 256 + j, isf), acc);
    h1[g * 256 + j] = selu_f(acc);
}
__global__ void k_mlp2(const float* __restrict__ h1, const void* __restrict__ W2,
                       const void* __restrict__ b2, float* __restrict__ h2,
                       const int* __restrict__ dflag)
{
    int isf = *dflag;
    int g = blockIdx.x, j = threadIdx.x;
    float acc = ldv(b2, j, isf);
    for (int k = 0; k < 256; k++)
        acc = fmaf(h1[g * 256 + k], ldv(W2, (ll)k * 256 + j, isf), acc);
    h2[g * 256 + j] = selu_f(acc);
}
__global__ void k_mlp3(const float* __restrict__ h2, const void* __restrict__ W3,
                       const void* __restrict__ b3, void* __restrict__ out,
                       const int* __restrict__ dflag)
{
    int isf = *dflag;
    int g = threadIdx.x;
    float acc = ldv(b3, 0, isf);
    for (int k = 0; k < 256; k++)
        acc = fmaf(h2[g * 256 + k], ldv(W3, k, isf), acc);
    if (isf) ((float*)out)[g] = acc;
    else     ((bf16*)out)[g] = __float2bfloat16(acc);
}

extern "C" void kernel_launch(void* const* d_in, const int* in_sizes, int n_in,
                              void* d_out, int out_size, void* d_ws, size_t ws_size,
                              hipStream_t stream)
{
    const void* graph_state = d_in[0];
    const void* node_state  = d_in[1];
    const int*  first   = (const int*)d_in[2];
    const int*  second  = (const int*)d_in[3];
    const int*  gid     = (const int*)d_in[4];
    const void* W_msg  = d_in[6];
    const void* b_msg  = d_in[7];
    const void* Wx_e   = d_in[8];
    const void* Wh_e   = d_in[9];
    const void* bx_e   = d_in[10];
    const void* bh_e   = d_in[11];
    const void* W_nmsg = d_in[12];
    const void* b_nmsg = d_in[13];
    const void* Wx_n   = d_in[14];
    const void* Wh_n   = d_in[15];
    const void* bx_n   = d_in[16];
    const void* bh_n   = d_in[17];
    const void* W1 = d_in[18];
    const void* b1 = d_in[19];
    const void* W2 = d_in[20];
    const void* b2 = d_in[21];
    const void* W3 = d_in[22];
    const void* b3 = d_in[23];

    const int E = in_sizes[0] / 64;   // 100000
    const int M = in_sizes[2];        // 300000

    // ---- compact workspace layout with overlays (total ~78.27 MB) ----
    float* ls   = (float*)d_ws;                    // [E*64]
    float* ns   = ls + (size_t)E * 64;             // [E*64]
    float* agg  = ns + (size_t)E * 64;             // [E*64]; sort scratch + pooledR overlay
    int*   perm = (int*)(agg + (size_t)E * 64);    // [M]; readout scratch overlay
    float* wb   = (float*)(perm + M);              // hot-path weights (66,432 floats)
    size_t o = 0;
    float* Wm_e  = wb + o; o += 8192;
    float* Wm_n  = wb + o; o += 8192;
    float* Gx_e  = wb + o; o += 12288;
    float* Gh_e  = wb + o; o += 12288;
    float* Gx_n  = wb + o; o += 12288;
    float* Gh_n  = wb + o; o += 12288;
    float* bm_e  = wb + o; o += 64;
    float* bm_n  = wb + o; o += 64;
    float* bgx_e = wb + o; o += 192;
    float* bgh_e = wb + o; o += 192;
    float* bgx_n = wb + o; o += 192;
    float* bgh_n = wb + o; o += 192;
    int*   dflag = (int*)(wb + o);
    // overlays: sort scratch lives in agg (dead until first memset+k_msg)
    int* cnt   = (int*)agg;      // [E]
    int* bsum  = cnt + E;        // [512]
    int* ebsum = bsum + 512;     // [512]
    // overlays: readout scratch lives in perm (dead after last k_msg)
    float* pooled  = (float*)perm;       // [256*128]
    float* h1      = pooled + 32768;     // [256*256]
    float* h2      = h1 + 65536;         // [256*256]  (total 163,840 <= M ints)
    float* pooledR = agg;                // [64*256*128] (readout only)

    // ---- dtype + init + weight prep ----
    k_detect<<<1, 64, 0, stream>>>((const unsigned short*)graph_state, dflag);
    k_init<<<(E * 64 + 255) / 256, 256, 0, stream>>>(graph_state, node_state, ls, ns, E, dflag);
    k_prep_msgW<<<32, 256, 0, stream>>>(Wm_e, W_msg, 64, 64, dflag);
    k_prep_msgW<<<32, 256, 0, stream>>>(Wm_n, W_nmsg, DNODE, DNODE, dflag);
    k_prep_gruW<<<48, 256, 0, stream>>>(Gx_e, Wx_e, 64, dflag);
    k_prep_gruW<<<48, 256, 0, stream>>>(Gh_e, Wh_e, 64, dflag);
    k_prep_gruW<<<48, 256, 0, stream>>>(Gx_n, Wx_n, DNODE, dflag);
    k_prep_gruW<<<48, 256, 0, stream>>>(Gh_n, Wh_n, DNODE, dflag);
    k_prep_padvec<<<1, 256, 0, stream>>>(bm_e, b_msg, 64, 64, dflag);
    k_prep_padvec<<<1, 256, 0, stream>>>(bm_n, b_nmsg, DNODE, 64, dflag);
    k_prep_grub<<<1, 256, 0, stream>>>(bgx_e, bx_e, 64, dflag);
    k_prep_grub<<<1, 256, 0, stream>>>(bgh_e, bh_e, 64, dflag);
    k_prep_grub<<<1, 256, 0, stream>>>(bgx_n, bx_n, DNODE, dflag);
    k_prep_grub<<<1, 256, 0, stream>>>(bgh_n, bh_n, DNODE, dflag);

    // ---- counting sort of pairs by `second` (scratch in agg; perm persists) ----
    const int NB = (E + 255) / 256;
    hipMemsetAsync(cnt, 0, (size_t)E * sizeof(int), stream);
    k_hist<<<(M + 255) / 256, 256, 0, stream>>>(second, cnt, M);
    k_scan_block<<<NB, 256, 0, stream>>>(cnt, bsum, E);
    k_scan_top<<<1, 64, 0, stream>>>(bsum, ebsum, NB);
    k_scan_add<<<NB, 256, 0, stream>>>(cnt, ebsum, E);
    k_scatter<<<(M + 255) / 256, 256, 0, stream>>>(second, cnt, perm, M);

    // ---- message passing ----
    const int mb = (M + 127) / 128;
    const int eb = (E + 63) / 64;
    for (int it = 0; it < 4; ++it) {
        hipMemsetAsync(agg, 0, (size_t)E * 64 * sizeof(float), stream);
        k_msg<<<mb, 256, 0, stream>>>(ls, first, second, perm, Wm_e, bm_e, agg, M);
        k_gru<<<eb, 256, 0, stream>>>(agg, ls, Gx_e, Gh_e, bgx_e, bgh_e, E);
    }
    for (int it = 0; it < 4; ++it) {
        hipMemsetAsync(agg, 0, (size_t)E * 64 * sizeof(float), stream);
        k_msg<<<mb, 256, 0, stream>>>(ns, first, second, perm, Wm_n, bm_n, agg, M);
        k_gru<<<eb, 256, 0, stream>>>(agg, ns, Gx_n, Gh_n, bgx_n, bgh_n, E);
    }

    // ---- readout (perm dead now; agg dead -> pooledR) ----
    hipMemsetAsync(pooledR, 0, (size_t)64 * NGRAPH * 128 * sizeof(float), stream);
    k_pool<<<(int)(((ll)E * 128 + 255) / 256), 256, 0, stream>>>(ls, ns, gid, pooledR, E);
    k_pool_red<<<(NGRAPH * 128) / 256, 256, 0, stream>>>(pooledR, pooled);
    k_mlp1<<<256, 256, 0, stream>>>(pooled, W1, b1, h1, dflag);
    k_mlp2<<<256, 256, 0, stream>>>(h1, W2, b2, h2, dflag);
    k_mlp3<<<1, 256, 0, stream>>>(h2, W3, b3, d_out, dflag);
}

// Round 6
// 1249.616 us; speedup vs baseline: 3.1407x; 1.5362x over previous
//
#include <hip/hip_runtime.h>
#include <hip/hip_bf16.h>

#define DNODE 59
#define NGRAPH 256
typedef __hip_bfloat16 bf16;
typedef long long ll;
typedef short short8v __attribute__((ext_vector_type(8)));
typedef float float4v __attribute__((ext_vector_type(4)));

__device__ __forceinline__ float b2f(bf16 x) { return __bfloat162float(x); }
__device__ __forceinline__ float ldv(const void* p, ll i, int isf) {
    return isf ? ((const float*)p)[i] : b2f(((const bf16*)p)[i]);
}
// fp32 -> bf16 bits (RNE)
__device__ __forceinline__ unsigned short f2bs(float x) {
    unsigned int u = __float_as_uint(x);
    u += 0x7fffu + ((u >> 16) & 1u);
    return (unsigned short)(u >> 16);
}
__device__ __forceinline__ unsigned int pk2(float a, float b) {
    return (unsigned int)f2bs(a) | ((unsigned int)f2bs(b) << 16);
}
__device__ __forceinline__ float selu_f(float x) {
    const float scale = 1.0507009873554805f;
    const float alpha = 1.6732632423543772f;
    return x > 0.f ? scale * x : scale * alpha * (__expf(x) - 1.f);
}
__device__ __forceinline__ float sigmoid_f(float x) { return 1.f / (1.f + __expf(-x)); }
__device__ __forceinline__ float tanh_f(float x) {
    float t = __expf(-2.f * fabsf(x));
    return copysignf((1.f - t) / (1.f + t), x);
}

// ---------------- dtype detector (bf16 vs fp32 tensors) --------------------------
__global__ void k_detect(const unsigned short* __restrict__ gsu, int* __restrict__ flag)
{
    if (threadIdx.x == 0 && blockIdx.x == 0) {
        int wild = 0;
        for (int i = 0; i < 512; ++i) {
            int e = (gsu[i] >> 7) & 0xFF;
            if (e >= 0x8F) wild++;
        }
        *flag = (wild >= 20) ? 1 : 0;
    }
}

// ---------------- init states -> fp32 (node padded to stride 64) -----------------
__global__ void k_init(const void* __restrict__ gs, const void* __restrict__ nsb,
                       float* __restrict__ ls, float* __restrict__ ns, int E,
                       const int* __restrict__ dflag)
{
    int isf = *dflag;
    int i = blockIdx.x * 256 + threadIdx.x;
    if (i >= E * 64) return;
    ls[i] = ldv(gs, i, isf);
    int e = i >> 6, c = i & 63;
    ns[i] = (c < DNODE) ? ldv(nsb, (ll)e * DNODE + c, isf) : 0.f;
}

// ---------------- weight prep: blocked bf16 for MFMA B-operands ------------------
// msg W [2*KH][NN] -> blocked [kb=k/8][col 0..63][k%8], k in [0,128): first half
// rows then second half, zero padded.
__global__ void k_prep_msgWb(short* __restrict__ dst, const void* __restrict__ src,
                             int KH, int NN, const int* __restrict__ dflag)
{
    int isf = *dflag;
    int i = blockIdx.x * 256 + threadIdx.x;
    if (i >= 128 * 64) return;
    int k = i >> 6, c = i & 63;
    int half = k >> 6, kk = k & 63;
    float v = 0.f;
    if (kk < KH && c < NN) v = ldv(src, (ll)(half * KH + kk) * NN + c, isf);
    dst[(k >> 3) * 512 + c * 8 + (k & 7)] = (short)f2bs(v);
}
// GRU W [D][3*D] -> blocked [kb=k/8][c 0..191][k%8], c = gate*64 + d, zero padded.
__global__ void k_prep_gruWb(short* __restrict__ dst, const void* __restrict__ src,
                             int D, const int* __restrict__ dflag)
{
    int isf = *dflag;
    int i = blockIdx.x * 256 + threadIdx.x;
    if (i >= 64 * 192) return;
    int k = i / 192, c = i % 192, g = c >> 6, d = c & 63;
    float v = 0.f;
    if (k < D && d < D) v = ldv(src, (ll)k * 3 * D + g * D + d, isf);
    dst[(k >> 3) * 1536 + c * 8 + (k & 7)] = (short)f2bs(v);
}
// GRU bias [3*D] -> [192] fp32
__global__ void k_prep_grub(float* __restrict__ dst, const void* __restrict__ src,
                            int D, const int* __restrict__ dflag)
{
    int t = threadIdx.x;
    if (t >= 192) return;
    int g = t >> 6, d = t & 63;
    dst[t] = (d < D) ? ldv(src, g * D + d, *dflag) : 0.f;
}
__global__ void k_prep_padvec(float* __restrict__ dst, const void* __restrict__ src,
                              int S, int D, const int* __restrict__ dflag)
{
    int i = blockIdx.x * 256 + threadIdx.x;
    if (i < D) dst[i] = (i < S) ? ldv(src, i, *dflag) : 0.f;
}

// ---------------- counting sort of pairs by `second` ------------------------------
__global__ void k_hist(const int* __restrict__ second, int* __restrict__ cnt, int M)
{
    int m = blockIdx.x * 256 + threadIdx.x;
    if (m < M) atomicAdd(&cnt[second[m]], 1);
}
__global__ void k_scan_block(int* __restrict__ cnt, int* __restrict__ bsum, int E)
{
    __shared__ int s[256];
    int t = threadIdx.x, i = blockIdx.x * 256 + t;
    int v = (i < E) ? cnt[i] : 0;
    s[t] = v;
    __syncthreads();
    #pragma unroll
    for (int d = 1; d < 256; d <<= 1) {
        int xv = (t >= d) ? s[t - d] : 0;
        __syncthreads();
        s[t] += xv;
        __syncthreads();
    }
    if (i < E) cnt[i] = s[t] - v;
    if (t == 255) bsum[blockIdx.x] = s[255];
}
__global__ void k_scan_top(const int* __restrict__ bsum, int* __restrict__ ebsum, int NB)
{
    if (threadIdx.x == 0 && blockIdx.x == 0) {
        int run = 0;
        for (int b = 0; b < NB; ++b) { ebsum[b] = run; run += bsum[b]; }
    }
}
__global__ void k_scan_add(int* __restrict__ cnt, const int* __restrict__ ebsum, int E)
{
    int i = blockIdx.x * 256 + threadIdx.x;
    if (i < E) cnt[i] += ebsum[blockIdx.x];
}
__global__ void k_scatter(const int* __restrict__ second, int* __restrict__ cnt,
                          int* __restrict__ perm, int M)
{
    int m = blockIdx.x * 256 + threadIdx.x;
    if (m < M) {
        int s = second[m];
        int pos = atomicAdd(&cnt[s], 1);
        perm[pos] = m;
    }
}

// ---------------- message: MFMA GEMM + sorted-run LDS segment reduce --------------
// 128 pairs x 64 cols, K=128 (padded concat). A staged bf16 in LDS blocked
// [kb][pair][8]; B (weights) read as fragments straight from L2-hot blocked global.
__launch_bounds__(256)
__global__ void k_msg(const float* __restrict__ state,
                      const int* __restrict__ first, const int* __restrict__ second,
                      const int* __restrict__ perm,
                      const short* __restrict__ Wmb,  // blocked [16][64][8] bf16
                      const float* __restrict__ bm,   // [64] fp32 padded
                      float* __restrict__ agg,        // [E][64], pre-zeroed
                      int M)
{
    __shared__ short As[4 * 132 * 8];   // [kb][pair pad 132][8] bf16 (8.45 KB)
    __shared__ float Ms[128 * 33];      // epilogue tile (16.9 KB)
    __shared__ float bias_s[64];
    __shared__ int fi[128], se[128];

    const int t  = threadIdx.x;
    const int m0 = blockIdx.x * 128;

    if (t < 128) {
        int m = m0 + t;
        if (m < M) { int pm_ = perm[m]; fi[t] = first[pm_]; se[t] = second[pm_]; }
        else       { fi[t] = 0; se[t] = -1; }
    } else if (t < 192) {
        bias_s[t - 128] = bm[t - 128];
    }

    const int lane = t & 63, wv = t >> 6;
    const int quad = lane >> 4, l16 = lane & 15;
    const int pm = wv * 32;             // wave's 32-pair row band

    float4v acc[2][4];
    #pragma unroll
    for (int i = 0; i < 2; i++)
        #pragma unroll
        for (int j = 0; j < 4; j++) acc[i][j] = (float4v){0.f, 0.f, 0.f, 0.f};

    for (int kc = 0; kc < 128; kc += 32) {
        __syncthreads();                 // covers index/bias staging on first pass
        // stage A chunk: gather fp32, convert bf16, k-blocked layout
        #pragma unroll
        for (int r = 0; r < 4; ++r) {
            int id = t + r * 256;        // 0..1023
            int p = id >> 3, q = id & 7;
            int kl = q * 4, kg = kc + kl;
            int row = (kg < 64) ? fi[p] : se[p];
            if (row < 0) row = 0;
            float4 v = *(const float4*)&state[(ll)row * 64 + (kg & 63)];
            unsigned int u0 = pk2(v.x, v.y), u1 = pk2(v.z, v.w);
            *(uint2*)&As[((kl >> 3) * 132 + p) * 8 + (kl & 7)] = make_uint2(u0, u1);
        }
        __syncthreads();
        // fragments + MFMA: 2 row tiles x 4 col tiles
        short8v a[2], b[4];
        #pragma unroll
        for (int tm = 0; tm < 2; ++tm)
            a[tm] = *(const short8v*)&As[(quad * 132 + pm + tm * 16 + l16) * 8];
        const int kbg = (kc >> 3) + quad;
        #pragma unroll
        for (int tn = 0; tn < 4; ++tn)
            b[tn] = *(const short8v*)&Wmb[(kbg * 64 + tn * 16 + l16) * 8];
        #pragma unroll
        for (int tm = 0; tm < 2; ++tm)
            #pragma unroll
            for (int tn = 0; tn < 4; ++tn)
                acc[tm][tn] = __builtin_amdgcn_mfma_f32_16x16x32_bf16(a[tm], b[tn], acc[tm][tn], 0, 0, 0);
    }

    // epilogue: +bias, selu -> Ms, sorted-run segment reduce, store
    #pragma unroll
    for (int hh = 0; hh < 2; ++hh) {
        __syncthreads();
        #pragma unroll
        for (int tm = 0; tm < 2; ++tm)
            #pragma unroll
            for (int tn2 = 0; tn2 < 2; ++tn2) {
                float4v c4 = acc[tm][hh * 2 + tn2];
                int c32 = tn2 * 16 + l16;
                #pragma unroll
                for (int r = 0; r < 4; ++r) {
                    int p = pm + tm * 16 + quad * 4 + r;
                    Ms[p * 33 + c32] = selu_f(c4[r] + bias_s[hh * 32 + c32]);
                }
            }
        __syncthreads();
        for (int cell = t; cell < 4096; cell += 256) {
            int p = cell >> 5, c32 = cell & 31;
            int dst = se[p];
            if (dst < 0) continue;
            if (p > 0 && se[p - 1] == dst) continue;   // not a run head
            float s = 0.f;
            int q = p;
            while (q < 128 && se[q] == dst) { s += Ms[q * 33 + c32]; ++q; }
            int col = hh * 32 + c32;
            if (p == 0 || q == 128) atomicAdd(&agg[(ll)dst * 64 + col], s);
            else                    agg[(ll)dst * 64 + col] = s;
        }
    }
}

// ---------------- fused GRU via MFMA: h = GRU(x=agg, h) in place ------------------
// 64 edges/block, both GEMMs [64 x 192 x 64] on matrix cores; gates in-register.
__launch_bounds__(256)
__global__ void k_gru(const float* __restrict__ x, float* __restrict__ h,
                      const short* __restrict__ Gxb, const short* __restrict__ Ghb, // [8][192][8] bf16
                      const float* __restrict__ bgx, const float* __restrict__ bgh, // [192]
                      int E)
{
    __shared__ short Axb[8 * 68 * 8], Ahb[8 * 68 * 8];   // [kb][edge pad 68][8] bf16
    __shared__ float bxs[192], bhs[192];

    const int t = threadIdx.x;
    const int e0 = blockIdx.x * 64;
    if (t < 192) { bxs[t] = bgx[t]; bhs[t] = bgh[t]; }

    // stage x and h (all K=64), bf16 blocked
    #pragma unroll
    for (int r = 0; r < 4; ++r) {
        int v = t + r * 256;            // 0..1023
        int el = v >> 4, q = v & 15;
        int e = e0 + el, kl = q * 4;
        float4 vx = make_float4(0.f, 0.f, 0.f, 0.f), vh = vx;
        if (e < E) {
            vx = *(const float4*)&x[(ll)e * 64 + kl];
            vh = *(const float4*)&h[(ll)e * 64 + kl];
        }
        int idx = ((kl >> 3) * 68 + el) * 8 + (kl & 7);
        *(uint2*)&Axb[idx] = make_uint2(pk2(vx.x, vx.y), pk2(vx.z, vx.w));
        *(uint2*)&Ahb[idx] = make_uint2(pk2(vh.x, vh.y), pk2(vh.z, vh.w));
    }
    __syncthreads();

    const int lane = t & 63, wv = t >> 6, quad = lane >> 4, l16 = lane & 15;
    const int em = wv * 16;             // wave's 16-edge tile

    float4v accx[12], acch[12];
    #pragma unroll
    for (int i = 0; i < 12; i++) { accx[i] = (float4v){0.f,0.f,0.f,0.f}; acch[i] = (float4v){0.f,0.f,0.f,0.f}; }

    #pragma unroll
    for (int c = 0; c < 2; ++c) {
        short8v a_x = *(const short8v*)&Axb[((c * 4 + quad) * 68 + em + l16) * 8];
        short8v a_h = *(const short8v*)&Ahb[((c * 4 + quad) * 68 + em + l16) * 8];
        const int kb = c * 4 + quad;
        #pragma unroll
        for (int tn = 0; tn < 12; ++tn) {
            short8v b_x = *(const short8v*)&Gxb[(kb * 192 + tn * 16 + l16) * 8];
            accx[tn] = __builtin_amdgcn_mfma_f32_16x16x32_bf16(a_x, b_x, accx[tn], 0, 0, 0);
            short8v b_h = *(const short8v*)&Ghb[(kb * 192 + tn * 16 + l16) * 8];
            acch[tn] = __builtin_amdgcn_mfma_f32_16x16x32_bf16(a_h, b_h, acch[tn], 0, 0, 0);
        }
    }

    // epilogue: gates (z, r, hh) fully in-register; fp32 h_old; in-place update
    #pragma unroll
    for (int r = 0; r < 4; ++r) {
        int e = e0 + em + quad * 4 + r;
        if (e >= E) continue;
        #pragma unroll
        for (int j = 0; j < 4; ++j) {
            int d = j * 16 + l16;
            float xz = accx[j][r]     + bxs[d];
            float xr = accx[4 + j][r] + bxs[64 + d];
            float xh = accx[8 + j][r] + bxs[128 + d];
            float hz = acch[j][r]     + bhs[d];
            float hr = acch[4 + j][r] + bhs[64 + d];
            float hv = acch[8 + j][r] + bhs[128 + d];
            float z  = sigmoid_f(xz + hz);
            float rr = sigmoid_f(xr + hr);
            float cc = tanh_f(xh + rr * hv);
            float ho = h[(ll)e * 64 + d];
            h[(ll)e * 64 + d] = z * ho + (1.f - z) * cc;
        }
    }
}

// ---------------- readout pool (64-way replicated atomics) -----------------------
__global__ void k_pool(const float* __restrict__ ls, const float* __restrict__ ns,
                       const int* __restrict__ gid, float* __restrict__ pooledR, int E)
{
    ll i = (ll)blockIdx.x * 256 + threadIdx.x;
    if (i >= (ll)E * 128) return;
    int e = (int)(i >> 7), c = (int)(i & 127);
    if (c >= 64 + DNODE) return;
    int g = gid[e];
    int rep = blockIdx.x & 63;
    float v = (c < 64) ? ls[(ll)e * 64 + c] : ns[(ll)e * 64 + (c - 64)];
    atomicAdd(&pooledR[((ll)rep * NGRAPH + g) * 128 + c], v);
}
__global__ void k_pool_red(const float* __restrict__ pooledR, float* __restrict__ pooled)
{
    int i = blockIdx.x * 256 + threadIdx.x;
    float s = 0.f;
    for (int r = 0; r < 64; ++r) s += pooledR[(ll)r * NGRAPH * 128 + i];
    pooled[i] = s;
}

// ---------------- readout MLP (raw weights via ldv; not a bottleneck) ------------
__global__ void k_mlp1(const float* __restrict__ pooled, const void* __restrict__ W1,
                       const void* __restrict__ b1, float* __restrict__ h1,
                       const int* __restrict__ dflag)
{
    int isf = *dflag;
    int g = blockIdx.x, j = threadIdx.x;
    float acc = ldv(b1, j, isf);
    for (int k = 0; k < 64 + DNODE; k++)
        acc = fmaf(pooled[g * 128 + k], ldv(W1, (ll)k * 256 + j, isf), acc);
    h1[g * 256 + j] = selu_f(acc);
}
__global__ void k_mlp2(const float* __restrict__ h1, const void* __restrict__ W2,
                       const void* __restrict__ b2, float* __restrict__ h2,
                       const int* __restrict__ dflag)
{
    int isf = *dflag;
    int g = blockIdx.x, j = threadIdx.x;
    float acc = ldv(b2, j, isf);
    for (int k = 0; k < 256; k++)
        acc = fmaf(h1[g * 256 + k], ldv(W2, (ll)k * 256 + j, isf), acc);
    h2[g * 256 + j] = selu_f(acc);
}
__global__ void k_mlp3(const float* __restrict__ h2, const void* __restrict__ W3,
                       const void* __restrict__ b3, void* __restrict__ out,
                       const int* __restrict__ dflag)
{
    int isf = *dflag;
    int g = threadIdx.x;
    float acc = ldv(b3, 0, isf);
    for (int k = 0; k < 256; k++)
        acc = fmaf(h2[g * 256 + k], ldv(W3, k, isf), acc);
    if (isf) ((float*)out)[g] = acc;
    else     ((bf16*)out)[g] = __float2bfloat16(acc);
}

extern "C" void kernel_launch(void* const* d_in, const int* in_sizes, int n_in,
                              void* d_out, int out_size, void* d_ws, size_t ws_size,
                              hipStream_t stream)
{
    const void* graph_state = d_in[0];
    const void* node_state  = d_in[1];
    const int*  first   = (const int*)d_in[2];
    const int*  second  = (const int*)d_in[3];
    const int*  gid     = (const int*)d_in[4];
    const void* W_msg  = d_in[6];
    const void* b_msg  = d_in[7];
    const void* Wx_e   = d_in[8];
    const void* Wh_e   = d_in[9];
    const void* bx_e   = d_in[10];
    const void* bh_e   = d_in[11];
    const void* W_nmsg = d_in[12];
    const void* b_nmsg = d_in[13];
    const void* Wx_n   = d_in[14];
    const void* Wh_n   = d_in[15];
    const void* bx_n   = d_in[16];
    const void* bh_n   = d_in[17];
    const void* W1 = d_in[18];
    const void* b1 = d_in[19];
    const void* W2 = d_in[20];
    const void* b2 = d_in[21];
    const void* W3 = d_in[22];
    const void* b3 = d_in[23];

    const int E = in_sizes[0] / 64;   // 100000
    const int M = in_sizes[2];        // 300000

    // ---- compact workspace layout with overlays ----
    float* ls   = (float*)d_ws;                    // [E*64]
    float* ns   = ls + (size_t)E * 64;             // [E*64]
    float* agg  = ns + (size_t)E * 64;             // [E*64]; sort scratch + pooledR overlay
    int*   perm = (int*)(agg + (size_t)E * 64);    // [M]; readout scratch overlay
    short* sb   = (short*)(perm + M);              // blocked bf16 weights (128 KB)
    size_t so = 0;
    short* Wmb_e = sb + so; so += 8192;
    short* Wmb_n = sb + so; so += 8192;
    short* Gxb_e = sb + so; so += 12288;
    short* Ghb_e = sb + so; so += 12288;
    short* Gxb_n = sb + so; so += 12288;
    short* Ghb_n = sb + so; so += 12288;
    float* fb = (float*)(sb + so);
    size_t fo = 0;
    float* bm_e  = fb + fo; fo += 64;
    float* bm_n  = fb + fo; fo += 64;
    float* bgx_e = fb + fo; fo += 192;
    float* bgh_e = fb + fo; fo += 192;
    float* bgx_n = fb + fo; fo += 192;
    float* bgh_n = fb + fo; fo += 192;
    int* dflag = (int*)(fb + fo);
    // overlays: sort scratch lives in agg (dead until first memset+k_msg)
    int* cnt   = (int*)agg;
    int* bsum  = cnt + E;
    int* ebsum = bsum + 512;
    // overlays: readout scratch lives in perm (dead after last k_msg)
    float* pooled  = (float*)perm;
    float* h1      = pooled + 32768;
    float* h2      = h1 + 65536;
    float* pooledR = agg;

    // ---- dtype + init + weight prep ----
    k_detect<<<1, 64, 0, stream>>>((const unsigned short*)graph_state, dflag);
    k_init<<<(E * 64 + 255) / 256, 256, 0, stream>>>(graph_state, node_state, ls, ns, E, dflag);
    k_prep_msgWb<<<32, 256, 0, stream>>>(Wmb_e, W_msg, 64, 64, dflag);
    k_prep_msgWb<<<32, 256, 0, stream>>>(Wmb_n, W_nmsg, DNODE, DNODE, dflag);
    k_prep_gruWb<<<48, 256, 0, stream>>>(Gxb_e, Wx_e, 64, dflag);
    k_prep_gruWb<<<48, 256, 0, stream>>>(Ghb_e, Wh_e, 64, dflag);
    k_prep_gruWb<<<48, 256, 0, stream>>>(Gxb_n, Wx_n, DNODE, dflag);
    k_prep_gruWb<<<48, 256, 0, stream>>>(Ghb_n, Wh_n, DNODE, dflag);
    k_prep_padvec<<<1, 256, 0, stream>>>(bm_e, b_msg, 64, 64, dflag);
    k_prep_padvec<<<1, 256, 0, stream>>>(bm_n, b_nmsg, DNODE, 64, dflag);
    k_prep_grub<<<1, 256, 0, stream>>>(bgx_e, bx_e, 64, dflag);
    k_prep_grub<<<1, 256, 0, stream>>>(bgh_e, bh_e, 64, dflag);
    k_prep_grub<<<1, 256, 0, stream>>>(bgx_n, bx_n, DNODE, dflag);
    k_prep_grub<<<1, 256, 0, stream>>>(bgh_n, bh_n, DNODE, dflag);

    // ---- counting sort of pairs by `second` ----
    const int NB = (E + 255) / 256;
    hipMemsetAsync(cnt, 0, (size_t)E * sizeof(int), stream);
    k_hist<<<(M + 255) / 256, 256, 0, stream>>>(second, cnt, M);
    k_scan_block<<<NB, 256, 0, stream>>>(cnt, bsum, E);
    k_scan_top<<<1, 64, 0, stream>>>(bsum, ebsum, NB);
    k_scan_add<<<NB, 256, 0, stream>>>(cnt, ebsum, E);
    k_scatter<<<(M + 255) / 256, 256, 0, stream>>>(second, cnt, perm, M);

    // ---- message passing ----
    const int mb = (M + 127) / 128;
    const int eb = (E + 63) / 64;
    for (int it = 0; it < 4; ++it) {
        hipMemsetAsync(agg, 0, (size_t)E * 64 * sizeof(float), stream);
        k_msg<<<mb, 256, 0, stream>>>(ls, first, second, perm, Wmb_e, bm_e, agg, M);
        k_gru<<<eb, 256, 0, stream>>>(agg, ls, Gxb_e, Ghb_e, bgx_e, bgh_e, E);
    }
    for (int it = 0; it < 4; ++it) {
        hipMemsetAsync(agg, 0, (size_t)E * 64 * sizeof(float), stream);
        k_msg<<<mb, 256, 0, stream>>>(ns, first, second, perm, Wmb_n, bm_n, agg, M);
        k_gru<<<eb, 256, 0, stream>>>(agg, ns, Gxb_n, Ghb_n, bgx_n, bgh_n, E);
    }

    // ---- readout ----
    hipMemsetAsync(pooledR, 0, (size_t)64 * NGRAPH * 128 * sizeof(float), stream);
    k_pool<<<(int)(((ll)E * 128 + 255) / 256), 256, 0, stream>>>(ls, ns, gid, pooledR, E);
    k_pool_red<<<(NGRAPH * 128) / 256, 256, 0, stream>>>(pooledR, pooled);
    k_mlp1<<<256, 256, 0, stream>>>(pooled, W1, b1, h1, dflag);
    k_mlp2<<<256, 256, 0, stream>>>(h1, W2, b2, h2, dflag);
    k_mlp3<<<1, 256, 0, stream>>>(h2, W3, b3, d_out, dflag);
}

// Round 7
// 1181.810 us; speedup vs baseline: 3.3209x; 1.0574x over previous
//
#include <hip/hip_runtime.h>
#include <hip/hip_bf16.h>

#define DNODE 59
#define NGRAPH 256
typedef __hip_bfloat16 bf16;
typedef long long ll;
typedef unsigned short ushort;
typedef short short8v __attribute__((ext_vector_type(8)));
typedef float float4v __attribute__((ext_vector_type(4)));

__device__ __forceinline__ float b2f(bf16 x) { return __bfloat162float(x); }
__device__ __forceinline__ float bs2f(ushort u) {
    unsigned int w = ((unsigned int)u) << 16;
    return __uint_as_float(w);
}
__device__ __forceinline__ float ldv(const void* p, ll i, int isf) {
    return isf ? ((const float*)p)[i] : b2f(((const bf16*)p)[i]);
}
// fp32 -> bf16 bits (RNE)
__device__ __forceinline__ ushort f2bs(float x) {
    unsigned int u = __float_as_uint(x);
    u += 0x7fffu + ((u >> 16) & 1u);
    return (ushort)(u >> 16);
}
__device__ __forceinline__ float selu_f(float x) {
    const float scale = 1.0507009873554805f;
    const float alpha = 1.6732632423543772f;
    return x > 0.f ? scale * x : scale * alpha * (__expf(x) - 1.f);
}
__device__ __forceinline__ float sigmoid_f(float x) { return 1.f / (1.f + __expf(-x)); }
__device__ __forceinline__ float tanh_f(float x) {
    float t = __expf(-2.f * fabsf(x));
    return copysignf((1.f - t) / (1.f + t), x);
}

// ---------------- dtype detector (bf16 vs fp32 tensors) --------------------------
__global__ void k_detect(const ushort* __restrict__ gsu, int* __restrict__ flag)
{
    if (threadIdx.x == 0 && blockIdx.x == 0) {
        int wild = 0;
        for (int i = 0; i < 512; ++i) {
            int e = (gsu[i] >> 7) & 0xFF;
            if (e >= 0x8F) wild++;
        }
        *flag = (wild >= 20) ? 1 : 0;
    }
}

// ---------------- init: input -> fp32 A + bf16 mirror ---------------------------
__global__ void k_init_ls(const void* __restrict__ gs, float* __restrict__ A,
                          ushort* __restrict__ B, int E, const int* __restrict__ dflag)
{
    int isf = *dflag;
    int i = blockIdx.x * 256 + threadIdx.x;
    if (i >= E * 64) return;
    float v = ldv(gs, i, isf);
    A[i] = v; B[i] = f2bs(v);
}
__global__ void k_init_ns(const void* __restrict__ nsb, float* __restrict__ A,
                          ushort* __restrict__ B, int E, const int* __restrict__ dflag)
{
    int isf = *dflag;
    int i = blockIdx.x * 256 + threadIdx.x;
    if (i >= E * 64) return;
    int e = i >> 6, c = i & 63;
    float v = (c < DNODE) ? ldv(nsb, (ll)e * DNODE + c, isf) : 0.f;
    A[i] = v; B[i] = f2bs(v);
}

// ---------------- weight prep: blocked bf16 for MFMA B-operands ------------------
__global__ void k_prep_msgWb(short* __restrict__ dst, const void* __restrict__ src,
                             int KH, int NN, const int* __restrict__ dflag)
{
    int isf = *dflag;
    int i = blockIdx.x * 256 + threadIdx.x;
    if (i >= 128 * 64) return;
    int k = i >> 6, c = i & 63;
    int half = k >> 6, kk = k & 63;
    float v = 0.f;
    if (kk < KH && c < NN) v = ldv(src, (ll)(half * KH + kk) * NN + c, isf);
    dst[(k >> 3) * 512 + c * 8 + (k & 7)] = (short)f2bs(v);
}
__global__ void k_prep_gruWb(short* __restrict__ dst, const void* __restrict__ src,
                             int D, const int* __restrict__ dflag)
{
    int isf = *dflag;
    int i = blockIdx.x * 256 + threadIdx.x;
    if (i >= 64 * 192) return;
    int k = i / 192, c = i % 192, g = c >> 6, d = c & 63;
    float v = 0.f;
    if (k < D && d < D) v = ldv(src, (ll)k * 3 * D + g * D + d, isf);
    dst[(k >> 3) * 1536 + c * 8 + (k & 7)] = (short)f2bs(v);
}
__global__ void k_prep_grub(float* __restrict__ dst, const void* __restrict__ src,
                            int D, const int* __restrict__ dflag)
{
    int t = threadIdx.x;
    if (t >= 192) return;
    int g = t >> 6, d = t & 63;
    dst[t] = (d < D) ? ldv(src, g * D + d, *dflag) : 0.f;
}
__global__ void k_prep_padvec(float* __restrict__ dst, const void* __restrict__ src,
                              int S, int D, const int* __restrict__ dflag)
{
    int i = blockIdx.x * 256 + threadIdx.x;
    if (i < D) dst[i] = (i < S) ? ldv(src, i, *dflag) : 0.f;
}

// ---------------- counting sort of pairs by `second` ------------------------------
__global__ void k_hist(const int* __restrict__ second, int* __restrict__ cnt, int M)
{
    int m = blockIdx.x * 256 + threadIdx.x;
    if (m < M) atomicAdd(&cnt[second[m]], 1);
}
__global__ void k_scan_block(int* __restrict__ cnt, int* __restrict__ bsum, int E)
{
    __shared__ int s[256];
    int t = threadIdx.x, i = blockIdx.x * 256 + t;
    int v = (i < E) ? cnt[i] : 0;
    s[t] = v;
    __syncthreads();
    #pragma unroll
    for (int d = 1; d < 256; d <<= 1) {
        int xv = (t >= d) ? s[t - d] : 0;
        __syncthreads();
        s[t] += xv;
        __syncthreads();
    }
    if (i < E) cnt[i] = s[t] - v;
    if (t == 255) bsum[blockIdx.x] = s[255];
}
__global__ void k_scan_top(const int* __restrict__ bsum, int* __restrict__ ebsum, int NB)
{
    if (threadIdx.x == 0 && blockIdx.x == 0) {
        int run = 0;
        for (int b = 0; b < NB; ++b) { ebsum[b] = run; run += bsum[b]; }
    }
}
__global__ void k_scan_add(int* __restrict__ cnt, const int* __restrict__ ebsum, int E)
{
    int i = blockIdx.x * 256 + threadIdx.x;
    if (i < E) cnt[i] += ebsum[blockIdx.x];
}
__global__ void k_scatter(const int* __restrict__ second, int* __restrict__ cnt,
                          int* __restrict__ perm, int M)
{
    int m = blockIdx.x * 256 + threadIdx.x;
    if (m < M) {
        int s = second[m];
        int pos = atomicAdd(&cnt[s], 1);
        perm[pos] = m;
    }
}

// ---------------- message: bf16 gather + MFMA + sorted-run reduce ----------------
// agg is bf16; interior runs plain-store, boundary runs -> bnd records (2/block).
__launch_bounds__(256)
__global__ void k_msg(const ushort* __restrict__ stateb,
                      const int* __restrict__ first, const int* __restrict__ second,
                      const int* __restrict__ perm,
                      const short* __restrict__ Wmb,  // blocked [16][64][8] bf16
                      const float* __restrict__ bm,   // [64] fp32 padded
                      ushort* __restrict__ aggb,      // [E][64] bf16, pre-zeroed
                      ushort* __restrict__ bndVal,    // [2*NB][64] bf16 partials
                      int* __restrict__ bndDst,       // [2*NB]
                      int M)
{
    // As (bf16 staging, [8 kb][132 pairs][8]) overlays Ms (fp32 [128][33]): both 16896 B
    __shared__ __align__(16) short AsU[8448];
    float* Ms = (float*)AsU;
    __shared__ float bias_s[64];
    __shared__ int fi[128], se[128];

    const int t  = threadIdx.x;
    const int b  = blockIdx.x;
    const int m0 = b * 128;

    if (t < 128) {
        int m = m0 + t;
        if (m < M) { int pm_ = perm[m]; fi[t] = first[pm_]; se[t] = second[pm_]; }
        else       { fi[t] = 0; se[t] = -1; }
    } else if (t < 192) {
        bias_s[t - 128] = bm[t - 128];
    }

    const int lane = t & 63, wv = t >> 6;
    const int quad = lane >> 4, l16 = lane & 15;
    const int pm = wv * 32;             // wave's 32-pair row band

    float4v acc[2][4];
    #pragma unroll
    for (int i = 0; i < 2; i++)
        #pragma unroll
        for (int j = 0; j < 4; j++) acc[i][j] = (float4v){0.f, 0.f, 0.f, 0.f};

    #pragma unroll
    for (int c = 0; c < 2; ++c) {       // chunk 0: first-rows (k 0..63); 1: second-rows
        __syncthreads();
        #pragma unroll
        for (int r = 0; r < 4; ++r) {
            int id = t + r * 256;       // 0..1023
            int p = id >> 3, q = id & 7;
            int row = c ? se[p] : fi[p];
            if (row < 0) row = 0;
            uint4 v = *(const uint4*)&stateb[(ll)row * 64 + q * 8];
            *(uint4*)&AsU[(q * 132 + p) * 8] = v;
        }
        __syncthreads();
        #pragma unroll
        for (int s = 0; s < 2; ++s) {
            short8v a[2], bf[4];
            const int kbl = s * 4 + quad;
            a[0] = *(const short8v*)&AsU[(kbl * 132 + pm + l16) * 8];
            a[1] = *(const short8v*)&AsU[(kbl * 132 + pm + 16 + l16) * 8];
            const int kbg = c * 8 + s * 4 + quad;
            #pragma unroll
            for (int tn = 0; tn < 4; ++tn)
                bf[tn] = *(const short8v*)&Wmb[(kbg * 64 + tn * 16 + l16) * 8];
            #pragma unroll
            for (int tm = 0; tm < 2; ++tm)
                #pragma unroll
                for (int tn = 0; tn < 4; ++tn)
                    acc[tm][tn] = __builtin_amdgcn_mfma_f32_16x16x32_bf16(a[tm], bf[tn], acc[tm][tn], 0, 0, 0);
        }
    }

    if (t == 0) {
        bndDst[b * 2] = se[0];
        bndDst[b * 2 + 1] = (se[127] >= 0 && se[127] != se[0]) ? se[127] : -1;
    }

    // epilogue: +bias, selu -> Ms (overlays AsU), sorted-run reduce, bf16 stores
    #pragma unroll
    for (int hh = 0; hh < 2; ++hh) {
        __syncthreads();
        #pragma unroll
        for (int tm = 0; tm < 2; ++tm)
            #pragma unroll
            for (int tn2 = 0; tn2 < 2; ++tn2) {
                float4v c4 = acc[tm][hh * 2 + tn2];
                int c32 = tn2 * 16 + l16;
                #pragma unroll
                for (int r = 0; r < 4; ++r) {
                    int p = pm + tm * 16 + quad * 4 + r;
                    Ms[p * 33 + c32] = selu_f(c4[r] + bias_s[hh * 32 + c32]);
                }
            }
        __syncthreads();
        for (int cell = t; cell < 4096; cell += 256) {
            int p = cell >> 5, c32 = cell & 31;
            int dst = se[p];
            if (dst < 0) continue;
            if (p > 0 && se[p - 1] == dst) continue;   // not a run head
            float s = 0.f;
            int q = p;
            while (q < 128 && se[q] == dst) { s += Ms[q * 33 + c32]; ++q; }
            int col = hh * 32 + c32;
            if (p == 0)          bndVal[(ll)(b * 2) * 64 + col] = f2bs(s);
            else if (q == 128)   bndVal[(ll)(b * 2 + 1) * 64 + col] = f2bs(s);
            else                 aggb[(ll)dst * 64 + col] = f2bs(s);
        }
    }
}

// ---------------- boundary fixup: sum same-dst records, write agg row ------------
__global__ void k_fix(const int* __restrict__ bndDst, const ushort* __restrict__ bndVal,
                      ushort* __restrict__ aggb, int NR)
{
    int idx = (blockIdx.x * 256 + threadIdx.x) >> 6;
    int lane = threadIdx.x & 63;
    if (idx >= NR) return;
    int dst = bndDst[idx];
    if (dst < 0) return;
    int pprev = idx - 1;
    while (pprev >= 0 && bndDst[pprev] < 0) --pprev;
    if (pprev >= 0 && bndDst[pprev] == dst) return;    // not head record
    float s = 0.f;
    for (int r = idx; r < NR; ++r) {
        int d = bndDst[r];
        if (d == dst) s += bs2f(bndVal[(ll)r * 64 + lane]);
        else if (d >= 0) break;
    }
    aggb[(ll)dst * 64 + lane] = f2bs(s);
}

// ---------------- fused GRU via MFMA: h = GRU(x=aggb, h) -------------------------
__launch_bounds__(256)
__global__ void k_gru(const ushort* __restrict__ xb, float* __restrict__ h,
                      ushort* __restrict__ hb,
                      const short* __restrict__ Gxb, const short* __restrict__ Ghb, // [8][192][8]
                      const float* __restrict__ bgx, const float* __restrict__ bgh, // [192]
                      int E)
{
    __shared__ __align__(16) short Axb[8 * 68 * 8], Ahb[8 * 68 * 8];
    __shared__ float bxs[192], bhs[192];

    const int t = threadIdx.x;
    const int e0 = blockIdx.x * 64;
    if (t < 192) { bxs[t] = bgx[t]; bhs[t] = bgh[t]; }

    // stage x and h: direct bf16 copies
    #pragma unroll
    for (int r = 0; r < 2; ++r) {
        int id = t + r * 256;            // 0..511
        int el = id >> 3, q = id & 7;
        int e = e0 + el;
        uint4 vx = {0u, 0u, 0u, 0u}, vh = {0u, 0u, 0u, 0u};
        if (e < E) {
            vx = *(const uint4*)&xb[(ll)e * 64 + q * 8];
            vh = *(const uint4*)&hb[(ll)e * 64 + q * 8];
        }
        *(uint4*)&Axb[(q * 68 + el) * 8] = vx;
        *(uint4*)&Ahb[(q * 68 + el) * 8] = vh;
    }
    __syncthreads();

    const int lane = t & 63, wv = t >> 6, quad = lane >> 4, l16 = lane & 15;
    const int em = wv * 16;

    float4v accx[12], acch[12];
    #pragma unroll
    for (int i = 0; i < 12; i++) { accx[i] = (float4v){0.f,0.f,0.f,0.f}; acch[i] = (float4v){0.f,0.f,0.f,0.f}; }

    #pragma unroll
    for (int c = 0; c < 2; ++c) {
        const int kb = c * 4 + quad;
        short8v a_x = *(const short8v*)&Axb[(kb * 68 + em + l16) * 8];
        short8v a_h = *(const short8v*)&Ahb[(kb * 68 + em + l16) * 8];
        #pragma unroll
        for (int tn = 0; tn < 12; ++tn) {
            short8v b_x = *(const short8v*)&Gxb[(kb * 192 + tn * 16 + l16) * 8];
            accx[tn] = __builtin_amdgcn_mfma_f32_16x16x32_bf16(a_x, b_x, accx[tn], 0, 0, 0);
            short8v b_h = *(const short8v*)&Ghb[(kb * 192 + tn * 16 + l16) * 8];
            acch[tn] = __builtin_amdgcn_mfma_f32_16x16x32_bf16(a_h, b_h, acch[tn], 0, 0, 0);
        }
    }

    // epilogue: gates (z, r, hh); fp32 h_old; write fp32 h + bf16 mirror
    #pragma unroll
    for (int r = 0; r < 4; ++r) {
        int e = e0 + em + quad * 4 + r;
        if (e >= E) continue;
        #pragma unroll
        for (int j = 0; j < 4; ++j) {
            int d = j * 16 + l16;
            float xz = accx[j][r]     + bxs[d];
            float xr = accx[4 + j][r] + bxs[64 + d];
            float xh = accx[8 + j][r] + bxs[128 + d];
            float hz = acch[j][r]     + bhs[d];
            float hr = acch[4 + j][r] + bhs[64 + d];
            float hv = acch[8 + j][r] + bhs[128 + d];
            float z  = sigmoid_f(xz + hz);
            float rr = sigmoid_f(xr + hr);
            float cc = tanh_f(xh + rr * hv);
            float ho = h[(ll)e * 64 + d];
            float hn = z * ho + (1.f - z) * cc;
            h[(ll)e * 64 + d]  = hn;
            hb[(ll)e * 64 + d] = f2bs(hn);
        }
    }
}

// ---------------- readout pool (link from bf16 mirror, node from fp32) -----------
__global__ void k_pool(const ushort* __restrict__ lsb, const float* __restrict__ nsA,
                       const int* __restrict__ gid, float* __restrict__ pooledR, int E)
{
    ll i = (ll)blockIdx.x * 256 + threadIdx.x;
    if (i >= (ll)E * 128) return;
    int e = (int)(i >> 7), c = (int)(i & 127);
    if (c >= 64 + DNODE) return;
    int g = gid[e];
    int rep = blockIdx.x & 63;
    float v = (c < 64) ? bs2f(lsb[(ll)e * 64 + c]) : nsA[(ll)e * 64 + (c - 64)];
    atomicAdd(&pooledR[((ll)rep * NGRAPH + g) * 128 + c], v);
}
__global__ void k_pool_red(const float* __restrict__ pooledR, float* __restrict__ pooled)
{
    int i = blockIdx.x * 256 + threadIdx.x;
    float s = 0.f;
    for (int r = 0; r < 64; ++r) s += pooledR[(ll)r * NGRAPH * 128 + i];
    pooled[i] = s;
}

// ---------------- readout MLP ----------------------------------------------------
__global__ void k_mlp1(const float* __restrict__ pooled, const void* __restrict__ W1,
                       const void* __restrict__ b1, float* __restrict__ h1,
                       const int* __restrict__ dflag)
{
    int isf = *dflag;
    int g = blockIdx.x, j = threadIdx.x;
    float acc = ldv(b1, j, isf);
    for (int k = 0; k < 64 + DNODE; k++)
        acc = fmaf(pooled[g * 128 + k], ldv(W1, (ll)k * 256 + j, isf), acc);
    h1[g * 256 + j] = selu_f(acc);
}
__global__ void k_mlp2(const float* __restrict__ h1, const void* __restrict__ W2,
                       const void* __restrict__ b2, float* __restrict__ h2,
                       const int* __restrict__ dflag)
{
    int isf = *dflag;
    int g = blockIdx.x, j = threadIdx.x;
    float acc = ldv(b2, j, isf);
    for (int k = 0; k < 256; k++)
        acc = fmaf(h1[g * 256 + k], ldv(W2, (ll)k * 256 + j, isf), acc);
    h2[g * 256 + j] = selu_f(acc);
}
__global__ void k_mlp3(const float* __restrict__ h2, const void* __restrict__ W3,
                       const void* __restrict__ b3, void* __restrict__ out,
                       const int* __restrict__ dflag)
{
    int isf = *dflag;
    int g = threadIdx.x;
    float acc = ldv(b3, 0, isf);
    for (int k = 0; k < 256; k++)
        acc = fmaf(h2[g * 256 + k], ldv(W3, k, isf), acc);
    if (isf) ((float*)out)[g] = acc;
    else     ((bf16*)out)[g] = __float2bfloat16(acc);
}

extern "C" void kernel_launch(void* const* d_in, const int* in_sizes, int n_in,
                              void* d_out, int out_size, void* d_ws, size_t ws_size,
                              hipStream_t stream)
{
    const void* graph_state = d_in[0];
    const void* node_state  = d_in[1];
    const int*  first   = (const int*)d_in[2];
    const int*  second  = (const int*)d_in[3];
    const int*  gid     = (const int*)d_in[4];
    const void* W_msg  = d_in[6];
    const void* b_msg  = d_in[7];
    const void* Wx_e   = d_in[8];
    const void* Wh_e   = d_in[9];
    const void* bx_e   = d_in[10];
    const void* bh_e   = d_in[11];
    const void* W_nmsg = d_in[12];
    const void* b_nmsg = d_in[13];
    const void* Wx_n   = d_in[14];
    const void* Wh_n   = d_in[15];
    const void* bx_n   = d_in[16];
    const void* bh_n   = d_in[17];
    const void* W1 = d_in[18];
    const void* b1 = d_in[19];
    const void* W2 = d_in[20];
    const void* b2 = d_in[21];
    const void* W3 = d_in[22];
    const void* b3 = d_in[23];

    const int E = in_sizes[0] / 64;   // 100000
    const int M = in_sizes[2];        // 300000
    const int mb = (M + 127) / 128;   // k_msg blocks
    const int NR = 2 * mb;            // boundary records

    // ---- workspace layout (~66 MB) ----
    float*  A    = (float*)d_ws;                   // fp32 active state [E*64]
    ushort* B1   = (ushort*)(A + (size_t)E * 64);  // bf16 link state  [E*64]
    ushort* B2   = B1 + (size_t)E * 64;            // bf16 node state  [E*64]
    ushort* aggb = B2 + (size_t)E * 64;            // bf16 agg [E*64]; overlays below
    int*    perm = (int*)(aggb + (size_t)E * 64);  // [M]; readout overlay
    ushort* bndVal = (ushort*)(perm + M);          // [NR*64]
    int*    bndDst = (int*)(bndVal + (size_t)NR * 64);
    short*  sb   = (short*)(bndDst + NR);          // blocked bf16 weights
    size_t so = 0;
    short* Wmb_e = sb + so; so += 8192;
    short* Wmb_n = sb + so; so += 8192;
    short* Gxb_e = sb + so; so += 12288;
    short* Ghb_e = sb + so; so += 12288;
    short* Gxb_n = sb + so; so += 12288;
    short* Ghb_n = sb + so; so += 12288;
    float* fb = (float*)(sb + so);
    size_t fo = 0;
    float* bm_e  = fb + fo; fo += 64;
    float* bm_n  = fb + fo; fo += 64;
    float* bgx_e = fb + fo; fo += 192;
    float* bgh_e = fb + fo; fo += 192;
    float* bgx_n = fb + fo; fo += 192;
    float* bgh_n = fb + fo; fo += 192;
    int* dflag = (int*)(fb + fo);
    // overlays: sort scratch + pooledR live in aggb; pooled/h1/h2 live in perm
    int* cnt   = (int*)aggb;
    int* bsum  = cnt + E;
    int* ebsum = bsum + 512;
    float* pooled  = (float*)perm;
    float* h1      = pooled + 32768;
    float* h2      = h1 + 65536;
    float* pooledR = (float*)aggb;   // 8.4 MB <= 12.8 MB

    // ---- dtype + link init + weight prep ----
    k_detect<<<1, 64, 0, stream>>>((const ushort*)graph_state, dflag);
    k_init_ls<<<(E * 64 + 255) / 256, 256, 0, stream>>>(graph_state, A, B1, E, dflag);
    k_prep_msgWb<<<32, 256, 0, stream>>>(Wmb_e, W_msg, 64, 64, dflag);
    k_prep_msgWb<<<32, 256, 0, stream>>>(Wmb_n, W_nmsg, DNODE, DNODE, dflag);
    k_prep_gruWb<<<48, 256, 0, stream>>>(Gxb_e, Wx_e, 64, dflag);
    k_prep_gruWb<<<48, 256, 0, stream>>>(Ghb_e, Wh_e, 64, dflag);
    k_prep_gruWb<<<48, 256, 0, stream>>>(Gxb_n, Wx_n, DNODE, dflag);
    k_prep_gruWb<<<48, 256, 0, stream>>>(Ghb_n, Wh_n, DNODE, dflag);
    k_prep_padvec<<<1, 256, 0, stream>>>(bm_e, b_msg, 64, 64, dflag);
    k_prep_padvec<<<1, 256, 0, stream>>>(bm_n, b_nmsg, DNODE, 64, dflag);
    k_prep_grub<<<1, 256, 0, stream>>>(bgx_e, bx_e, 64, dflag);
    k_prep_grub<<<1, 256, 0, stream>>>(bgh_e, bh_e, 64, dflag);
    k_prep_grub<<<1, 256, 0, stream>>>(bgx_n, bx_n, DNODE, dflag);
    k_prep_grub<<<1, 256, 0, stream>>>(bgh_n, bh_n, DNODE, dflag);

    // ---- counting sort of pairs by `second` (scratch overlays aggb) ----
    const int NB = (E + 255) / 256;
    hipMemsetAsync(cnt, 0, (size_t)E * sizeof(int), stream);
    k_hist<<<(M + 255) / 256, 256, 0, stream>>>(second, cnt, M);
    k_scan_block<<<NB, 256, 0, stream>>>(cnt, bsum, E);
    k_scan_top<<<1, 64, 0, stream>>>(bsum, ebsum, NB);
    k_scan_add<<<NB, 256, 0, stream>>>(cnt, ebsum, E);
    k_scatter<<<(M + 255) / 256, 256, 0, stream>>>(second, cnt, perm, M);

    // ---- link message passing ----
    const int eb = (E + 63) / 64;
    const int fixb = (NR * 64 + 255) / 256;
    for (int it = 0; it < 4; ++it) {
        hipMemsetAsync(aggb, 0, (size_t)E * 64 * sizeof(ushort), stream);
        k_msg<<<mb, 256, 0, stream>>>(B1, first, second, perm, Wmb_e, bm_e, aggb, bndVal, bndDst, M);
        k_fix<<<fixb, 256, 0, stream>>>(bndDst, bndVal, aggb, NR);
        k_gru<<<eb, 256, 0, stream>>>(aggb, A, B1, Gxb_e, Ghb_e, bgx_e, bgh_e, E);
    }

    // ---- node phase: A is re-initialized to node state (link kept in B1 bf16) ----
    k_init_ns<<<(E * 64 + 255) / 256, 256, 0, stream>>>(node_state, A, B2, E, dflag);
    for (int it = 0; it < 4; ++it) {
        hipMemsetAsync(aggb, 0, (size_t)E * 64 * sizeof(ushort), stream);
        k_msg<<<mb, 256, 0, stream>>>(B2, first, second, perm, Wmb_n, bm_n, aggb, bndVal, bndDst, M);
        k_fix<<<fixb, 256, 0, stream>>>(bndDst, bndVal, aggb, NR);
        k_gru<<<eb, 256, 0, stream>>>(aggb, A, B2, Gxb_n, Ghb_n, bgx_n, bgh_n, E);
    }

    // ---- readout ----
    hipMemsetAsync(pooledR, 0, (size_t)64 * NGRAPH * 128 * sizeof(float), stream);
    k_pool<<<(int)(((ll)E * 128 + 255) / 256), 256, 0, stream>>>(B1, A, gid, pooledR, E);
    k_pool_red<<<(NGRAPH * 128) / 256, 256, 0, stream>>>(pooledR, pooled);
    k_mlp1<<<256, 256, 0, stream>>>(pooled, W1, b1, h1, dflag);
    k_mlp2<<<256, 256, 0, stream>>>(h1, W2, b2, h2, dflag);
    k_mlp3<<<1, 256, 0, stream>>>(h2, W3, b3, d_out, dflag);
}

// Round 8
// 1156.332 us; speedup vs baseline: 3.3941x; 1.0220x over previous
//
#include <hip/hip_runtime.h>
#include <hip/hip_bf16.h>

#define DNODE 59
#define NGRAPH 256
typedef __hip_bfloat16 bf16;
typedef long long ll;
typedef unsigned short ushort;
typedef short short8v __attribute__((ext_vector_type(8)));
typedef float float4v __attribute__((ext_vector_type(4)));

__device__ __forceinline__ float b2f(bf16 x) { return __bfloat162float(x); }
__device__ __forceinline__ float bs2f(ushort u) {
    return __uint_as_float(((unsigned int)u) << 16);
}
__device__ __forceinline__ float ldv(const void* p, ll i, int isf) {
    return isf ? ((const float*)p)[i] : b2f(((const bf16*)p)[i]);
}
__device__ __forceinline__ ushort f2bs(float x) {   // RNE
    unsigned int u = __float_as_uint(x);
    u += 0x7fffu + ((u >> 16) & 1u);
    return (ushort)(u >> 16);
}
__device__ __forceinline__ float selu_f(float x) {
    const float scale = 1.0507009873554805f;
    const float alpha = 1.6732632423543772f;
    return x > 0.f ? scale * x : scale * alpha * (__expf(x) - 1.f);
}
__device__ __forceinline__ float sigmoid_f(float x) { return 1.f / (1.f + __expf(-x)); }
__device__ __forceinline__ float tanh_f(float x) {
    float t = __expf(-2.f * fabsf(x));
    return copysignf((1.f - t) / (1.f + t), x);
}

// ---------------- dtype detector (bf16 vs fp32 tensors) --------------------------
__global__ void k_detect(const ushort* __restrict__ gsu, int* __restrict__ flag)
{
    if (threadIdx.x == 0 && blockIdx.x == 0) {
        int wild = 0;
        for (int i = 0; i < 512; ++i) {
            int e = (gsu[i] >> 7) & 0xFF;
            if (e >= 0x8F) wild++;
        }
        *flag = (wild >= 20) ? 1 : 0;
    }
}

// ---------------- init: input -> bf16 state mirrors ------------------------------
__global__ void k_init_ls(const void* __restrict__ gs, ushort* __restrict__ B, int E,
                          const int* __restrict__ dflag)
{
    int isf = *dflag;
    int i = blockIdx.x * 256 + threadIdx.x;
    if (i >= E * 64) return;
    B[i] = f2bs(ldv(gs, i, isf));
}
__global__ void k_init_ns(const void* __restrict__ nsb, ushort* __restrict__ B, int E,
                          const int* __restrict__ dflag)
{
    int isf = *dflag;
    int i = blockIdx.x * 256 + threadIdx.x;
    if (i >= E * 64) return;
    int e = i >> 6, c = i & 63;
    B[i] = (c < DNODE) ? f2bs(ldv(nsb, (ll)e * DNODE + c, isf)) : 0;
}

// ---------------- weight prep: blocked bf16 for MFMA B-operands ------------------
__global__ void k_prep_msgWb(short* __restrict__ dst, const void* __restrict__ src,
                             int KH, int NN, const int* __restrict__ dflag)
{
    int isf = *dflag;
    int i = blockIdx.x * 256 + threadIdx.x;
    if (i >= 128 * 64) return;
    int k = i >> 6, c = i & 63;
    int half = k >> 6, kk = k & 63;
    float v = 0.f;
    if (kk < KH && c < NN) v = ldv(src, (ll)(half * KH + kk) * NN + c, isf);
    dst[(k >> 3) * 512 + c * 8 + (k & 7)] = (short)f2bs(v);
}
__global__ void k_prep_gruWb(short* __restrict__ dst, const void* __restrict__ src,
                             int D, const int* __restrict__ dflag)
{
    int isf = *dflag;
    int i = blockIdx.x * 256 + threadIdx.x;
    if (i >= 64 * 192) return;
    int k = i / 192, c = i % 192, g = c >> 6, d = c & 63;
    float v = 0.f;
    if (k < D && d < D) v = ldv(src, (ll)k * 3 * D + g * D + d, isf);
    dst[(k >> 3) * 1536 + c * 8 + (k & 7)] = (short)f2bs(v);
}
__global__ void k_prep_grub(float* __restrict__ dst, const void* __restrict__ src,
                            int D, const int* __restrict__ dflag)
{
    int t = threadIdx.x;
    if (t >= 192) return;
    int g = t >> 6, d = t & 63;
    dst[t] = (d < D) ? ldv(src, g * D + d, *dflag) : 0.f;
}
__global__ void k_prep_padvec(float* __restrict__ dst, const void* __restrict__ src,
                              int S, int D, const int* __restrict__ dflag)
{
    int i = blockIdx.x * 256 + threadIdx.x;
    if (i < D) dst[i] = (i < S) ? ldv(src, i, *dflag) : 0.f;
}

// ---------------- counting sort of pairs by `second` ------------------------------
__global__ void k_hist(const int* __restrict__ second, int* __restrict__ cnt, int M)
{
    int m = blockIdx.x * 256 + threadIdx.x;
    if (m < M) atomicAdd(&cnt[second[m]], 1);
}
__global__ void k_scan_block(int* __restrict__ cnt, int* __restrict__ bsum, int E)
{
    __shared__ int s[256];
    int t = threadIdx.x, i = blockIdx.x * 256 + t;
    int v = (i < E) ? cnt[i] : 0;
    s[t] = v;
    __syncthreads();
    #pragma unroll
    for (int d = 1; d < 256; d <<= 1) {
        int xv = (t >= d) ? s[t - d] : 0;
        __syncthreads();
        s[t] += xv;
        __syncthreads();
    }
    if (i < E) cnt[i] = s[t] - v;
    if (t == 255) bsum[blockIdx.x] = s[255];
}
__global__ void k_scan_top(const int* __restrict__ bsum, int* __restrict__ ebsum, int NB)
{
    if (threadIdx.x == 0 && blockIdx.x == 0) {
        int run = 0;
        for (int b = 0; b < NB; ++b) { ebsum[b] = run; run += bsum[b]; }
    }
}
__global__ void k_scan_add(int* __restrict__ cnt, const int* __restrict__ ebsum, int E)
{
    int i = blockIdx.x * 256 + threadIdx.x;
    if (i < E) cnt[i] += ebsum[blockIdx.x];
}
// scatter writes pre-gathered sorted index arrays directly (no perm round-trip)
__global__ void k_scatter(const int* __restrict__ first, const int* __restrict__ second,
                          int* __restrict__ cnt, int* __restrict__ fiS,
                          int* __restrict__ seS, int M)
{
    int m = blockIdx.x * 256 + threadIdx.x;
    if (m < M) {
        int s = second[m];
        int pos = atomicAdd(&cnt[s], 1);
        fiS[pos] = first[m];
        seS[pos] = second[m];
    }
}

// ---------------- combined message kernel: link + node phases --------------------
// 256 sorted pairs/block; bf16 gather -> pair-major LDS -> MFMA -> selu ->
// sorted-run segment reduce; boundary runs to bnd records.
__launch_bounds__(256)
__global__ void k_msg2(const ushort* __restrict__ B1, const ushort* __restrict__ B2,
                       const int* __restrict__ fiS, const int* __restrict__ seS,
                       const short* __restrict__ Wmb_e, const short* __restrict__ Wmb_n,
                       const float* __restrict__ bm_e, const float* __restrict__ bm_n,
                       ushort* __restrict__ aggL, ushort* __restrict__ aggN,
                       ushort* __restrict__ bndVal, int* __restrict__ bndDst,
                       int M, int mb2)
{
    // As (pair-major bf16 [256 pairs][9 kb][8]) overlays Ms (fp32 [256][33])
    __shared__ __align__(16) short AsU[256 * 9 * 8];    // 36,864 B
    float* Ms = (float*)AsU;                            // 33,792 B
    __shared__ float bias_s[64];
    __shared__ int fi[256], se[256];

    const int b = blockIdx.x;
    const int phase = (b >= mb2) ? 1 : 0;
    const ushort* stateb = phase ? B2 : B1;
    const short* Wmb = phase ? Wmb_n : Wmb_e;
    ushort* aggb = phase ? aggN : aggL;
    const int m0 = (b - phase * mb2) * 256;
    const int t = threadIdx.x;

    {
        int m = m0 + t;
        fi[t] = (m < M) ? fiS[m] : 0;
        se[t] = (m < M) ? seS[m] : -1;
        if (t < 64) bias_s[t] = phase ? bm_n[t] : bm_e[t];
    }

    const int lane = t & 63, wv = t >> 6;
    const int quad = lane >> 4, l16 = lane & 15;
    const int pm = wv * 64;             // wave's 64-pair band

    float4v acc[4][4];
    #pragma unroll
    for (int i = 0; i < 4; i++)
        #pragma unroll
        for (int j = 0; j < 4; j++) acc[i][j] = (float4v){0.f, 0.f, 0.f, 0.f};

    #pragma unroll
    for (int c = 0; c < 2; ++c) {       // chunk 0: first-rows; 1: second-rows
        __syncthreads();                // also covers index/bias staging on c==0
        #pragma unroll
        for (int r = 0; r < 8; ++r) {
            int id = t + r * 256;       // 0..2047
            int p = id >> 3, q = id & 7;
            int row = c ? se[p] : fi[p];
            if (row < 0) row = 0;
            uint4 v = *(const uint4*)&stateb[(ll)row * 64 + q * 8];
            *(uint4*)&AsU[(p * 9 + q) * 8] = v;   // pair-major, pad slot 9
        }
        __syncthreads();
        #pragma unroll
        for (int s = 0; s < 2; ++s) {
            const int kbl = s * 4 + quad;
            short8v a[4], bf[4];
            #pragma unroll
            for (int tm = 0; tm < 4; ++tm)
                a[tm] = *(const short8v*)&AsU[((pm + tm * 16 + l16) * 9 + kbl) * 8];
            const int kbg = c * 8 + kbl;
            #pragma unroll
            for (int tn = 0; tn < 4; ++tn)
                bf[tn] = *(const short8v*)&Wmb[(kbg * 64 + tn * 16 + l16) * 8];
            #pragma unroll
            for (int tm = 0; tm < 4; ++tm)
                #pragma unroll
                for (int tn = 0; tn < 4; ++tn)
                    acc[tm][tn] = __builtin_amdgcn_mfma_f32_16x16x32_bf16(a[tm], bf[tn], acc[tm][tn], 0, 0, 0);
        }
    }

    if (t == 0) {
        bndDst[b * 2] = se[0];
        bndDst[b * 2 + 1] = (se[255] >= 0 && se[255] != se[0]) ? se[255] : -1;
    }

    // epilogue: +bias, selu -> Ms (overlays AsU), sorted-run reduce, bf16 stores
    #pragma unroll
    for (int hh = 0; hh < 2; ++hh) {
        __syncthreads();
        #pragma unroll
        for (int tm = 0; tm < 4; ++tm)
            #pragma unroll
            for (int tn2 = 0; tn2 < 2; ++tn2) {
                float4v c4 = acc[tm][hh * 2 + tn2];
                int c32 = tn2 * 16 + l16;
                #pragma unroll
                for (int r = 0; r < 4; ++r) {
                    int p = pm + tm * 16 + quad * 4 + r;
                    Ms[p * 33 + c32] = selu_f(c4[r] + bias_s[hh * 32 + c32]);
                }
            }
        __syncthreads();
        for (int cell = t; cell < 8192; cell += 256) {
            int p = cell >> 5, c32 = cell & 31;
            int dst = se[p];
            if (dst < 0) continue;
            if (p > 0 && se[p - 1] == dst) continue;   // not a run head
            float s = 0.f;
            int q = p;
            while (q < 256 && se[q] == dst) { s += Ms[q * 33 + c32]; ++q; }
            int col = hh * 32 + c32;
            if (p == 0)        bndVal[(ll)(b * 2) * 64 + col] = f2bs(s);
            else if (q == 256) bndVal[(ll)(b * 2 + 1) * 64 + col] = f2bs(s);
            else               aggb[(ll)dst * 64 + col] = f2bs(s);
        }
    }
}

// ---------------- boundary fixup (both phases) -----------------------------------
__global__ void k_fix2(const int* __restrict__ bndDst, const ushort* __restrict__ bndVal,
                       ushort* __restrict__ aggL, ushort* __restrict__ aggN, int NR2)
{
    int idx = (blockIdx.x * 256 + threadIdx.x) >> 6;
    int lane = threadIdx.x & 63;
    if (idx >= 2 * NR2) return;
    int phase = (idx >= NR2) ? 1 : 0;
    int ps = phase * NR2, pe = ps + NR2;
    ushort* aggb = phase ? aggN : aggL;
    int dst = bndDst[idx];
    if (dst < 0) return;
    int pprev = idx - 1;
    while (pprev >= ps && bndDst[pprev] < 0) --pprev;
    if (pprev >= ps && bndDst[pprev] == dst) return;   // not head record
    float s = 0.f;
    for (int r = idx; r < pe; ++r) {
        int d = bndDst[r];
        if (d == dst) s += bs2f(bndVal[(ll)r * 64 + lane]);
        else if (d >= 0) break;
    }
    aggb[(ll)dst * 64 + lane] = f2bs(s);
}

// ---------------- combined GRU: both phases, pure-bf16 state ---------------------
__launch_bounds__(256)
__global__ void k_gru2(const ushort* __restrict__ aggL, const ushort* __restrict__ aggN,
                       ushort* __restrict__ B1, ushort* __restrict__ B2,
                       const short* __restrict__ Gxb_e, const short* __restrict__ Ghb_e,
                       const short* __restrict__ Gxb_n, const short* __restrict__ Ghb_n,
                       const float* __restrict__ bgx_e, const float* __restrict__ bgh_e,
                       const float* __restrict__ bgx_n, const float* __restrict__ bgh_n,
                       int E, int eb)
{
    __shared__ __align__(16) short Axb[64 * 9 * 8], Ahb[64 * 9 * 8];  // 9,216 B each
    __shared__ float bxs[192], bhs[192];

    const int blk = blockIdx.x;
    const int phase = (blk >= eb) ? 1 : 0;
    const ushort* xb = phase ? aggN : aggL;
    ushort* hb = phase ? B2 : B1;
    const short* Gxb = phase ? Gxb_n : Gxb_e;
    const short* Ghb = phase ? Ghb_n : Ghb_e;
    const int e0 = (blk - phase * eb) * 64;
    const int t = threadIdx.x;

    if (t < 192) {
        bxs[t] = phase ? bgx_n[t] : bgx_e[t];
        bhs[t] = phase ? bgh_n[t] : bgh_e[t];
    }

    // stage x and h: bf16 copies, pair-major padded layout
    #pragma unroll
    for (int r = 0; r < 2; ++r) {
        int id = t + r * 256;            // 0..511
        int el = id >> 3, q = id & 7;
        int e = e0 + el;
        uint4 vx = {0u, 0u, 0u, 0u}, vh = {0u, 0u, 0u, 0u};
        if (e < E) {
            vx = *(const uint4*)&xb[(ll)e * 64 + q * 8];
            vh = *(const uint4*)&hb[(ll)e * 64 + q * 8];
        }
        *(uint4*)&Axb[(el * 9 + q) * 8] = vx;
        *(uint4*)&Ahb[(el * 9 + q) * 8] = vh;
    }
    __syncthreads();

    const int lane = t & 63, wv = t >> 6, quad = lane >> 4, l16 = lane & 15;
    const int em = wv * 16;

    float4v accx[12], acch[12];
    #pragma unroll
    for (int i = 0; i < 12; i++) { accx[i] = (float4v){0.f,0.f,0.f,0.f}; acch[i] = (float4v){0.f,0.f,0.f,0.f}; }

    #pragma unroll
    for (int c = 0; c < 2; ++c) {
        const int kb = c * 4 + quad;
        short8v a_x = *(const short8v*)&Axb[((em + l16) * 9 + kb) * 8];
        short8v a_h = *(const short8v*)&Ahb[((em + l16) * 9 + kb) * 8];
        #pragma unroll
        for (int tn = 0; tn < 12; ++tn) {
            short8v b_x = *(const short8v*)&Gxb[(kb * 192 + tn * 16 + l16) * 8];
            accx[tn] = __builtin_amdgcn_mfma_f32_16x16x32_bf16(a_x, b_x, accx[tn], 0, 0, 0);
            short8v b_h = *(const short8v*)&Ghb[(kb * 192 + tn * 16 + l16) * 8];
            acch[tn] = __builtin_amdgcn_mfma_f32_16x16x32_bf16(a_h, b_h, acch[tn], 0, 0, 0);
        }
    }

    // epilogue: gates (z, r, hh); h_old read back from the staged LDS tile
    #pragma unroll
    for (int r = 0; r < 4; ++r) {
        int el = em + quad * 4 + r;
        int e = e0 + el;
        if (e >= E) continue;
        #pragma unroll
        for (int j = 0; j < 4; ++j) {
            int d = j * 16 + l16;
            float xz = accx[j][r]     + bxs[d];
            float xr = accx[4 + j][r] + bxs[64 + d];
            float xh = accx[8 + j][r] + bxs[128 + d];
            float hz = acch[j][r]     + bhs[d];
            float hr = acch[4 + j][r] + bhs[64 + d];
            float hv = acch[8 + j][r] + bhs[128 + d];
            float z  = sigmoid_f(xz + hz);
            float rr = sigmoid_f(xr + hr);
            float cc = tanh_f(xh + rr * hv);
            float ho = bs2f((ushort)Ahb[(el * 9 + (d >> 3)) * 8 + (d & 7)]);
            hb[(ll)e * 64 + d] = f2bs(z * ho + (1.f - z) * cc);
        }
    }
}

// ---------------- readout pool (both states bf16) --------------------------------
__global__ void k_pool(const ushort* __restrict__ lsb, const ushort* __restrict__ nsb,
                       const int* __restrict__ gid, float* __restrict__ pooledR, int E)
{
    ll i = (ll)blockIdx.x * 256 + threadIdx.x;
    if (i >= (ll)E * 128) return;
    int e = (int)(i >> 7), c = (int)(i & 127);
    if (c >= 64 + DNODE) return;
    int g = gid[e];
    int rep = blockIdx.x & 63;
    float v = (c < 64) ? bs2f(lsb[(ll)e * 64 + c]) : bs2f(nsb[(ll)e * 64 + (c - 64)]);
    atomicAdd(&pooledR[((ll)rep * NGRAPH + g) * 128 + c], v);
}
__global__ void k_pool_red(const float* __restrict__ pooledR, float* __restrict__ pooled)
{
    int i = blockIdx.x * 256 + threadIdx.x;
    float s = 0.f;
    for (int r = 0; r < 64; ++r) s += pooledR[(ll)r * NGRAPH * 128 + i];
    pooled[i] = s;
}

// ---------------- readout MLP ----------------------------------------------------
__global__ void k_mlp1(const float* __restrict__ pooled, const void* __restrict__ W1,
                       const void* __restrict__ b1, float* __restrict__ h1,
                       const int* __restrict__ dflag)
{
    int isf = *dflag;
    int g = blockIdx.x, j = threadIdx.x;
    float acc = ldv(b1, j, isf);
    for (int k = 0; k < 64 + DNODE; k++)
        acc = fmaf(pooled[g * 128 + k], ldv(W1, (ll)k * 256 + j, isf), acc);
    h1[g * 256 + j] = selu_f(acc);
}
__global__ void k_mlp2(const float* __restrict__ h1, const void* __restrict__ W2,
                       const void* __restrict__ b2, float* __restrict__ h2,
                       const int* __restrict__ dflag)
{
    int isf = *dflag;
    int g = blockIdx.x, j = threadIdx.x;
    float acc = ldv(b2, j, isf);
    for (int k = 0; k < 256; k++)
        acc = fmaf(h1[g * 256 + k], ldv(W2, (ll)k * 256 + j, isf), acc);
    h2[g * 256 + j] = selu_f(acc);
}
__global__ void k_mlp3(const float* __restrict__ h2, const void* __restrict__ W3,
                       const void* __restrict__ b3, void* __restrict__ out,
                       const int* __restrict__ dflag)
{
    int isf = *dflag;
    int g = threadIdx.x;
    float acc = ldv(b3, 0, isf);
    for (int k = 0; k < 256; k++)
        acc = fmaf(h2[g * 256 + k], ldv(W3, k, isf), acc);
    if (isf) ((float*)out)[g] = acc;
    else     ((bf16*)out)[g] = __float2bfloat16(acc);
}

extern "C" void kernel_launch(void* const* d_in, const int* in_sizes, int n_in,
                              void* d_out, int out_size, void* d_ws, size_t ws_size,
                              hipStream_t stream)
{
    const void* graph_state = d_in[0];
    const void* node_state  = d_in[1];
    const int*  first   = (const int*)d_in[2];
    const int*  second  = (const int*)d_in[3];
    const int*  gid     = (const int*)d_in[4];
    const void* W_msg  = d_in[6];
    const void* b_msg  = d_in[7];
    const void* Wx_e   = d_in[8];
    const void* Wh_e   = d_in[9];
    const void* bx_e   = d_in[10];
    const void* bh_e   = d_in[11];
    const void* W_nmsg = d_in[12];
    const void* b_nmsg = d_in[13];
    const void* Wx_n   = d_in[14];
    const void* Wh_n   = d_in[15];
    const void* bx_n   = d_in[16];
    const void* bh_n   = d_in[17];
    const void* W1 = d_in[18];
    const void* b1 = d_in[19];
    const void* W2 = d_in[20];
    const void* b2 = d_in[21];
    const void* W3 = d_in[22];
    const void* b3 = d_in[23];

    const int E = in_sizes[0] / 64;    // 100000
    const int M = in_sizes[2];         // 300000
    const int mb2 = (M + 255) / 256;   // k_msg2 blocks per phase
    const int NR2 = 2 * mb2;           // boundary records per phase
    const int eb  = (E + 63) / 64;     // k_gru2 blocks per phase

    // ---- workspace layout (~55 MB) ----
    ushort* B1   = (ushort*)d_ws;                  // bf16 link state [E*64]
    ushort* B2   = B1 + (size_t)E * 64;            // bf16 node state [E*64]
    ushort* aggL = B2 + (size_t)E * 64;            // bf16 agg link   [E*64]
    ushort* aggN = aggL + (size_t)E * 64;          // bf16 agg node   [E*64] (contiguous)
    int*    fiS  = (int*)(aggN + (size_t)E * 64);  // sorted-gathered first [M]
    int*    seS  = fiS + M;                        // sorted second [M]
    ushort* bndVal = (ushort*)(seS + M);           // [2*NR2 * 64]
    int*    bndDst = (int*)(bndVal + (size_t)2 * NR2 * 64);
    short*  sb   = (short*)(bndDst + 2 * NR2);     // blocked bf16 weights
    size_t so = 0;
    short* Wmb_e = sb + so; so += 8192;
    short* Wmb_n = sb + so; so += 8192;
    short* Gxb_e = sb + so; so += 12288;
    short* Ghb_e = sb + so; so += 12288;
    short* Gxb_n = sb + so; so += 12288;
    short* Ghb_n = sb + so; so += 12288;
    float* fb = (float*)(sb + so);
    size_t fo = 0;
    float* bm_e  = fb + fo; fo += 64;
    float* bm_n  = fb + fo; fo += 64;
    float* bgx_e = fb + fo; fo += 192;
    float* bgh_e = fb + fo; fo += 192;
    float* bgx_n = fb + fo; fo += 192;
    float* bgh_n = fb + fo; fo += 192;
    int* dflag = (int*)(fb + fo);
    // overlays: sort scratch + pooledR live in aggL/aggN; pooled/h1/h2 in fiS
    int* cnt   = (int*)aggL;
    int* bsum  = cnt + E;
    int* ebsum = bsum + 512;
    float* pooledR = (float*)aggL;       // 8.4 MB <= 25.6 MB
    float* pooled  = (float*)fiS;        // readout only (fiS dead after last k_msg2)
    float* h1      = pooled + 32768;
    float* h2      = h1 + 65536;

    // ---- dtype + init + weight prep ----
    k_detect<<<1, 64, 0, stream>>>((const ushort*)graph_state, dflag);
    k_init_ls<<<(E * 64 + 255) / 256, 256, 0, stream>>>(graph_state, B1, E, dflag);
    k_init_ns<<<(E * 64 + 255) / 256, 256, 0, stream>>>(node_state, B2, E, dflag);
    k_prep_msgWb<<<32, 256, 0, stream>>>(Wmb_e, W_msg, 64, 64, dflag);
    k_prep_msgWb<<<32, 256, 0, stream>>>(Wmb_n, W_nmsg, DNODE, DNODE, dflag);
    k_prep_gruWb<<<48, 256, 0, stream>>>(Gxb_e, Wx_e, 64, dflag);
    k_prep_gruWb<<<48, 256, 0, stream>>>(Ghb_e, Wh_e, 64, dflag);
    k_prep_gruWb<<<48, 256, 0, stream>>>(Gxb_n, Wx_n, DNODE, dflag);
    k_prep_gruWb<<<48, 256, 0, stream>>>(Ghb_n, Wh_n, DNODE, dflag);
    k_prep_padvec<<<1, 256, 0, stream>>>(bm_e, b_msg, 64, 64, dflag);
    k_prep_padvec<<<1, 256, 0, stream>>>(bm_n, b_nmsg, DNODE, 64, dflag);
    k_prep_grub<<<1, 256, 0, stream>>>(bgx_e, bx_e, 64, dflag);
    k_prep_grub<<<1, 256, 0, stream>>>(bgh_e, bh_e, 64, dflag);
    k_prep_grub<<<1, 256, 0, stream>>>(bgx_n, bx_n, DNODE, dflag);
    k_prep_grub<<<1, 256, 0, stream>>>(bgh_n, bh_n, DNODE, dflag);

    // ---- counting sort by `second` -> fiS/seS (scratch overlays aggL) ----
    const int NB = (E + 255) / 256;
    hipMemsetAsync(cnt, 0, (size_t)E * sizeof(int), stream);
    k_hist<<<(M + 255) / 256, 256, 0, stream>>>(second, cnt, M);
    k_scan_block<<<NB, 256, 0, stream>>>(cnt, bsum, E);
    k_scan_top<<<1, 64, 0, stream>>>(bsum, ebsum, NB);
    k_scan_add<<<NB, 256, 0, stream>>>(cnt, ebsum, E);
    k_scatter<<<(M + 255) / 256, 256, 0, stream>>>(first, second, cnt, fiS, seS, M);

    // ---- message passing: link + node phases fused per launch ----
    const int fixb = (2 * NR2 * 64 + 255) / 256;
    for (int it = 0; it < 4; ++it) {
        hipMemsetAsync(aggL, 0, (size_t)2 * E * 64 * sizeof(ushort), stream);
        k_msg2<<<2 * mb2, 256, 0, stream>>>(B1, B2, fiS, seS, Wmb_e, Wmb_n, bm_e, bm_n,
                                            aggL, aggN, bndVal, bndDst, M, mb2);
        k_fix2<<<fixb, 256, 0, stream>>>(bndDst, bndVal, aggL, aggN, NR2);
        k_gru2<<<2 * eb, 256, 0, stream>>>(aggL, aggN, B1, B2,
                                           Gxb_e, Ghb_e, Gxb_n, Ghb_n,
                                           bgx_e, bgh_e, bgx_n, bgh_n, E, eb);
    }

    // ---- readout ----
    hipMemsetAsync(pooledR, 0, (size_t)64 * NGRAPH * 128 * sizeof(float), stream);
    k_pool<<<(int)(((ll)E * 128 + 255) / 256), 256, 0, stream>>>(B1, B2, gid, pooledR, E);
    k_pool_red<<<(NGRAPH * 128) / 256, 256, 0, stream>>>(pooledR, pooled);
    k_mlp1<<<256, 256, 0, stream>>>(pooled, W1, b1, h1, dflag);
    k_mlp2<<<256, 256, 0, stream>>>(h1, W2, b2, h2, dflag);
    k_mlp3<<<1, 256, 0, stream>>>(h2, W3, b3, d_out, dflag);
}

// Round 9
// 1062.825 us; speedup vs baseline: 3.6927x; 1.0880x over previous
//
#include <hip/hip_runtime.h>
#include <hip/hip_bf16.h>

#define DNODE 59
#define NGRAPH 256
typedef __hip_bfloat16 bf16;
typedef long long ll;
typedef unsigned short ushort;
typedef short short8v __attribute__((ext_vector_type(8)));
typedef float float4v __attribute__((ext_vector_type(4)));

__device__ __forceinline__ float b2f(bf16 x) { return __bfloat162float(x); }
__device__ __forceinline__ float bs2f(ushort u) {
    return __uint_as_float(((unsigned int)u) << 16);
}
__device__ __forceinline__ float ldv(const void* p, ll i, int isf) {
    return isf ? ((const float*)p)[i] : b2f(((const bf16*)p)[i]);
}
__device__ __forceinline__ ushort f2bs(float x) {   // RNE
    unsigned int u = __float_as_uint(x);
    u += 0x7fffu + ((u >> 16) & 1u);
    return (ushort)(u >> 16);
}
__device__ __forceinline__ float selu_f(float x) {
    const float scale = 1.0507009873554805f;
    const float alpha = 1.6732632423543772f;
    return x > 0.f ? scale * x : scale * alpha * (__expf(x) - 1.f);
}
__device__ __forceinline__ float sigmoid_f(float x) { return 1.f / (1.f + __expf(-x)); }
__device__ __forceinline__ float tanh_f(float x) {
    float t = __expf(-2.f * fabsf(x));
    return copysignf((1.f - t) / (1.f + t), x);
}

// ---------------- dtype detector (bf16 vs fp32 tensors) --------------------------
__global__ void k_detect(const ushort* __restrict__ gsu, int* __restrict__ flag)
{
    if (threadIdx.x == 0 && blockIdx.x == 0) {
        int wild = 0;
        for (int i = 0; i < 512; ++i) {
            int e = (gsu[i] >> 7) & 0xFF;
            if (e >= 0x8F) wild++;
        }
        *flag = (wild >= 20) ? 1 : 0;
    }
}

// ---------------- init: input -> bf16 state mirrors ------------------------------
__global__ void k_init_ls(const void* __restrict__ gs, ushort* __restrict__ B, int E,
                          const int* __restrict__ dflag)
{
    int isf = *dflag;
    int i = blockIdx.x * 256 + threadIdx.x;
    if (i >= E * 64) return;
    B[i] = f2bs(ldv(gs, i, isf));
}
__global__ void k_init_ns(const void* __restrict__ nsb, ushort* __restrict__ B, int E,
                          const int* __restrict__ dflag)
{
    int isf = *dflag;
    int i = blockIdx.x * 256 + threadIdx.x;
    if (i >= E * 64) return;
    int e = i >> 6, c = i & 63;
    B[i] = (c < DNODE) ? f2bs(ldv(nsb, (ll)e * DNODE + c, isf)) : 0;
}

// ---------------- weight prep ----------------------------------------------------
// msg W [2*KH][NN] -> PQ blocked [8 kb][128 cols][8]: cols 0-63 = W_top (main half),
// cols 64-127 = W_bot (neighbor half), zero padded.
__global__ void k_prep_pqWb(short* __restrict__ dst, const void* __restrict__ src,
                            int KH, int NN, const int* __restrict__ dflag)
{
    int isf = *dflag;
    int i = blockIdx.x * 256 + threadIdx.x;
    if (i >= 64 * 128) return;
    int k = i >> 7, j = i & 127;
    int half = j >> 6, c = j & 63;
    float v = 0.f;
    if (k < KH && c < NN) v = ldv(src, (ll)(half * KH + k) * NN + c, isf);
    dst[(k >> 3) * 1024 + j * 8 + (k & 7)] = (short)f2bs(v);
}
// GRU W [D][3*D] -> blocked [8 kb][192 cols][8], col = gate*64+d, zero padded.
__global__ void k_prep_gruWb(short* __restrict__ dst, const void* __restrict__ src,
                             int D, const int* __restrict__ dflag)
{
    int isf = *dflag;
    int i = blockIdx.x * 256 + threadIdx.x;
    if (i >= 64 * 192) return;
    int k = i / 192, c = i % 192, g = c >> 6, d = c & 63;
    float v = 0.f;
    if (k < D && d < D) v = ldv(src, (ll)k * 3 * D + g * D + d, isf);
    dst[(k >> 3) * 1536 + c * 8 + (k & 7)] = (short)f2bs(v);
}
__global__ void k_prep_grub(float* __restrict__ dst, const void* __restrict__ src,
                            int D, const int* __restrict__ dflag)
{
    int t = threadIdx.x;
    if (t >= 192) return;
    int g = t >> 6, d = t & 63;
    dst[t] = (d < D) ? ldv(src, g * D + d, *dflag) : 0.f;
}
__global__ void k_prep_padvec(float* __restrict__ dst, const void* __restrict__ src,
                              int S, int D, const int* __restrict__ dflag)
{
    int i = blockIdx.x * 256 + threadIdx.x;
    if (i < D) dst[i] = (i < S) ? ldv(src, i, *dflag) : 0.f;
}

// ---------------- counting sort of pairs by `second` ------------------------------
__global__ void k_hist(const int* __restrict__ second, int* __restrict__ cnt, int M)
{
    int m = blockIdx.x * 256 + threadIdx.x;
    if (m < M) atomicAdd(&cnt[second[m]], 1);
}
__global__ void k_scan_block(int* __restrict__ cnt, int* __restrict__ bsum, int E)
{
    __shared__ int s[256];
    int t = threadIdx.x, i = blockIdx.x * 256 + t;
    int v = (i < E) ? cnt[i] : 0;
    s[t] = v;
    __syncthreads();
    #pragma unroll
    for (int d = 1; d < 256; d <<= 1) {
        int xv = (t >= d) ? s[t - d] : 0;
        __syncthreads();
        s[t] += xv;
        __syncthreads();
    }
    if (i < E) cnt[i] = s[t] - v;
    if (t == 255) bsum[blockIdx.x] = s[255];
}
__global__ void k_scan_top(const int* __restrict__ bsum, int* __restrict__ ebsum, int NB)
{
    if (threadIdx.x == 0 && blockIdx.x == 0) {
        int run = 0;
        for (int b = 0; b < NB; ++b) { ebsum[b] = run; run += bsum[b]; }
    }
}
__global__ void k_scan_add(int* __restrict__ cnt, const int* __restrict__ ebsum, int E)
{
    int i = blockIdx.x * 256 + threadIdx.x;
    if (i < E) cnt[i] += ebsum[blockIdx.x];
}
__global__ void k_scatter(const int* __restrict__ first, const int* __restrict__ second,
                          int* __restrict__ cnt, int* __restrict__ fiS,
                          int* __restrict__ seS, int M)
{
    int m = blockIdx.x * 256 + threadIdx.x;
    if (m < M) {
        int s = second[m];
        int pos = atomicAdd(&cnt[s], 1);
        fiS[pos] = first[m];
        seS[pos] = second[m];
    }
}

// ---------------- dense PQ GEMM: PQ[e] = B[e] @ [W_top | W_bot], also zero agg ----
__launch_bounds__(256)
__global__ void k_pq(const ushort* __restrict__ B, const short* __restrict__ Wb,
                     ushort* __restrict__ PQ, ushort* __restrict__ aggz, int E)
{
    __shared__ __align__(16) short Ms16[64 * 136];   // 17,408 B relay
    const int t = threadIdx.x;
    const int e0 = blockIdx.x * 64;
    const int lane = t & 63, wv = t >> 6, quad = lane >> 4, l16 = lane & 15;
    const int em = wv * 16;

    int er = e0 + em + l16; if (er >= E) er = E - 1;

    float4v acc[8];
    #pragma unroll
    for (int i = 0; i < 8; ++i) acc[i] = (float4v){0.f, 0.f, 0.f, 0.f};

    #pragma unroll
    for (int c = 0; c < 2; ++c) {
        int kb = c * 4 + quad;
        short8v a = *(const short8v*)&B[(ll)er * 64 + kb * 8];
        #pragma unroll
        for (int tn = 0; tn < 8; ++tn) {
            short8v bw = *(const short8v*)&Wb[(kb * 128 + tn * 16 + l16) * 8];
            acc[tn] = __builtin_amdgcn_mfma_f32_16x16x32_bf16(a, bw, acc[tn], 0, 0, 0);
        }
    }

    // zero agg rows for this block (independent of the GEMM)
    #pragma unroll
    for (int r = 0; r < 2; ++r) {
        int id = t + r * 256;
        int row = id >> 3, q = id & 7;
        if (e0 + row < E)
            *(uint4*)&aggz[(ll)(e0 + row) * 64 + q * 8] = make_uint4(0u, 0u, 0u, 0u);
    }

    // relay acc -> bf16 LDS -> coalesced PQ store
    #pragma unroll
    for (int tn = 0; tn < 8; ++tn)
        #pragma unroll
        for (int r = 0; r < 4; ++r)
            Ms16[(em + quad * 4 + r) * 136 + tn * 16 + l16] = (short)f2bs(acc[tn][r]);
    __syncthreads();
    #pragma unroll
    for (int r = 0; r < 4; ++r) {
        int id = t + r * 256;       // 0..1023
        int row = id >> 4, q = id & 15;
        if (e0 + row < E)
            *(uint4*)&PQ[(ll)(e0 + row) * 128 + q * 8] = *(uint4*)&Ms16[row * 136 + q * 8];
    }
}

// ---------------- scatter-agg over sorted runs: one wave per 64-pair span ---------
// agg[e] = sum_{m: se[m]==e} selu(P[fi[m]] + Q[e] + bias). Uniform control flow,
// coalesced 128B row loads, interior runs plain-store, span edges -> bnd records.
__launch_bounds__(256)
__global__ void k_scat(const ushort* __restrict__ PQ,
                       const int* __restrict__ fiS, const int* __restrict__ seS,
                       const float* __restrict__ bm,
                       ushort* __restrict__ aggb,
                       ushort* __restrict__ bndVal, int* __restrict__ bndDst,
                       int M)
{
    const int lane = threadIdx.x & 63, wv = threadIdx.x >> 6;
    const int sp = blockIdx.x * 4 + wv;
    const int m0 = sp * 64;
    const float bb = bm[lane];

    int mm = m0 + lane;
    int fiv = (mm < M) ? fiS[mm] : 0;
    int sev = (mm < M) ? seS[mm] : -1;

    int cur = __shfl(sev, 0);
    if (cur < 0) {                      // empty span (shouldn't happen, but safe)
        if (lane == 0) { bndDst[2 * sp] = -1; bndDst[2 * sp + 1] = -1; }
        return;
    }
    float qb = bs2f(PQ[(ll)cur * 128 + 64 + lane]) + bb;
    float sum = 0.f;
    bool headDone = false;
    int fv = __shfl(fiv, 0);
    float pv = bs2f(PQ[(ll)fv * 128 + lane]);

    for (int i = 0; i < 64; ++i) {
        int sv = __shfl(sev, i);
        if (sv < 0) break;
        float pnext = 0.f;
        if (i < 63) {                   // prefetch next P row (index always valid)
            int fn = __shfl(fiv, i + 1);
            pnext = bs2f(PQ[(ll)fn * 128 + lane]);
        }
        if (sv != cur) {
            if (!headDone) {
                bndVal[(ll)(2 * sp) * 64 + lane] = f2bs(sum);
                if (lane == 0) bndDst[2 * sp] = cur;
                headDone = true;
            } else {
                aggb[(ll)cur * 64 + lane] = f2bs(sum);
            }
            cur = sv;
            qb = bs2f(PQ[(ll)cur * 128 + 64 + lane]) + bb;
            sum = 0.f;
        }
        sum += selu_f(pv + qb);
        pv = pnext;
    }
    if (!headDone) {                    // whole span one run
        bndVal[(ll)(2 * sp) * 64 + lane] = f2bs(sum);
        if (lane == 0) { bndDst[2 * sp] = cur; bndDst[2 * sp + 1] = -1; }
    } else {
        bndVal[(ll)(2 * sp + 1) * 64 + lane] = f2bs(sum);
        if (lane == 0) bndDst[2 * sp + 1] = cur;
    }
}

// ---------------- boundary fixup: merge chained records per destination ----------
__global__ void k_fix(const int* __restrict__ bndDst, const ushort* __restrict__ bndVal,
                      ushort* __restrict__ aggb, int NR)
{
    int idx = (blockIdx.x * 256 + threadIdx.x) >> 6;
    int lane = threadIdx.x & 63;
    if (idx >= NR) return;
    int dst = bndDst[idx];
    if (dst < 0) return;
    int pprev = idx - 1;
    while (pprev >= 0 && bndDst[pprev] < 0) --pprev;
    if (pprev >= 0 && bndDst[pprev] == dst) return;    // not chain head
    float s = 0.f;
    for (int r = idx; r < NR; ++r) {
        int d = bndDst[r];
        if (d == dst) s += bs2f(bndVal[(ll)r * 64 + lane]);
        else if (d >= 0) break;
    }
    aggb[(ll)dst * 64 + lane] = f2bs(s);
}

// ---------------- GRU: barrier-free, direct-global MFMA fragments ----------------
__launch_bounds__(256)
__global__ void k_gru(const ushort* __restrict__ xb, ushort* __restrict__ hb,
                      const short* __restrict__ Gxb, const short* __restrict__ Ghb,
                      const float* __restrict__ bgx, const float* __restrict__ bgh,
                      int E)
{
    const int t = threadIdx.x;
    const int e0 = blockIdx.x * 64;
    const int lane = t & 63, wv = t >> 6, quad = lane >> 4, l16 = lane & 15;
    const int em = wv * 16;
    int er = e0 + em + l16; if (er >= E) er = E - 1;

    float4v accx[12], acch[12];
    #pragma unroll
    for (int i = 0; i < 12; ++i) { accx[i] = (float4v){0.f,0.f,0.f,0.f}; acch[i] = (float4v){0.f,0.f,0.f,0.f}; }

    #pragma unroll
    for (int c = 0; c < 2; ++c) {
        int kb = c * 4 + quad;
        short8v a_x = *(const short8v*)&xb[(ll)er * 64 + kb * 8];
        short8v a_h = *(const short8v*)&hb[(ll)er * 64 + kb * 8];
        #pragma unroll
        for (int tn = 0; tn < 12; ++tn) {
            short8v b_x = *(const short8v*)&Gxb[(kb * 192 + tn * 16 + l16) * 8];
            accx[tn] = __builtin_amdgcn_mfma_f32_16x16x32_bf16(a_x, b_x, accx[tn], 0, 0, 0);
            short8v b_h = *(const short8v*)&Ghb[(kb * 192 + tn * 16 + l16) * 8];
            acch[tn] = __builtin_amdgcn_mfma_f32_16x16x32_bf16(a_h, b_h, acch[tn], 0, 0, 0);
        }
    }

    // epilogue: gates (z, r, hh); h_old from L1-hot global; in-place bf16 update
    #pragma unroll
    for (int r = 0; r < 4; ++r) {
        int e = e0 + em + quad * 4 + r;
        if (e >= E) continue;
        #pragma unroll
        for (int j = 0; j < 4; ++j) {
            int d = j * 16 + l16;
            float xz = accx[j][r]     + bgx[d];
            float xr = accx[4 + j][r] + bgx[64 + d];
            float xh = accx[8 + j][r] + bgx[128 + d];
            float hz = acch[j][r]     + bgh[d];
            float hr = acch[4 + j][r] + bgh[64 + d];
            float hv = acch[8 + j][r] + bgh[128 + d];
            float z  = sigmoid_f(xz + hz);
            float rr = sigmoid_f(xr + hr);
            float cc = tanh_f(xh + rr * hv);
            float ho = bs2f(hb[(ll)e * 64 + d]);
            hb[(ll)e * 64 + d] = f2bs(z * ho + (1.f - z) * cc);
        }
    }
}

// ---------------- readout pool (64-way replicated atomics) -----------------------
__global__ void k_pool(const ushort* __restrict__ lsb, const ushort* __restrict__ nsb,
                       const int* __restrict__ gid, float* __restrict__ pooledR, int E)
{
    ll i = (ll)blockIdx.x * 256 + threadIdx.x;
    if (i >= (ll)E * 128) return;
    int e = (int)(i >> 7), c = (int)(i & 127);
    if (c >= 64 + DNODE) return;
    int g = gid[e];
    int rep = blockIdx.x & 63;
    float v = (c < 64) ? bs2f(lsb[(ll)e * 64 + c]) : bs2f(nsb[(ll)e * 64 + (c - 64)]);
    atomicAdd(&pooledR[((ll)rep * NGRAPH + g) * 128 + c], v);
}
__global__ void k_pool_red(const float* __restrict__ pooledR, float* __restrict__ pooled)
{
    int i = blockIdx.x * 256 + threadIdx.x;
    float s = 0.f;
    for (int r = 0; r < 64; ++r) s += pooledR[(ll)r * NGRAPH * 128 + i];
    pooled[i] = s;
}

// ---------------- readout MLP ----------------------------------------------------
__global__ void k_mlp1(const float* __restrict__ pooled, const void* __restrict__ W1,
                       const void* __restrict__ b1, float* __restrict__ h1,
                       const int* __restrict__ dflag)
{
    int isf = *dflag;
    int g = blockIdx.x, j = threadIdx.x;
    float acc = ldv(b1, j, isf);
    for (int k = 0; k < 64 + DNODE; k++)
        acc = fmaf(pooled[g * 128 + k], ldv(W1, (ll)k * 256 + j, isf), acc);
    h1[g * 256 + j] = selu_f(acc);
}
__global__ void k_mlp2(const float* __restrict__ h1, const void* __restrict__ W2,
                       const void* __restrict__ b2, float* __restrict__ h2,
                       const int* __restrict__ dflag)
{
    int isf = *dflag;
    int g = blockIdx.x, j = threadIdx.x;
    float acc = ldv(b2, j, isf);
    for (int k = 0; k < 256; k++)
        acc = fmaf(h1[g * 256 + k], ldv(W2, (ll)k * 256 + j, isf), acc);
    h2[g * 256 + j] = selu_f(acc);
}
__global__ void k_mlp3(const float* __restrict__ h2, const void* __restrict__ W3,
                       const void* __restrict__ b3, void* __restrict__ out,
                       const int* __restrict__ dflag)
{
    int isf = *dflag;
    int g = threadIdx.x;
    float acc = ldv(b3, 0, isf);
    for (int k = 0; k < 256; k++)
        acc = fmaf(h2[g * 256 + k], ldv(W3, k, isf), acc);
    if (isf) ((float*)out)[g] = acc;
    else     ((bf16*)out)[g] = __float2bfloat16(acc);
}

extern "C" void kernel_launch(void* const* d_in, const int* in_sizes, int n_in,
                              void* d_out, int out_size, void* d_ws, size_t ws_size,
                              hipStream_t stream)
{
    const void* graph_state = d_in[0];
    const void* node_state  = d_in[1];
    const int*  first   = (const int*)d_in[2];
    const int*  second  = (const int*)d_in[3];
    const int*  gid     = (const int*)d_in[4];
    const void* W_msg  = d_in[6];
    const void* b_msg  = d_in[7];
    const void* Wx_e   = d_in[8];
    const void* Wh_e   = d_in[9];
    const void* bx_e   = d_in[10];
    const void* bh_e   = d_in[11];
    const void* W_nmsg = d_in[12];
    const void* b_nmsg = d_in[13];
    const void* Wx_n   = d_in[14];
    const void* Wh_n   = d_in[15];
    const void* bx_n   = d_in[16];
    const void* bh_n   = d_in[17];
    const void* W1 = d_in[18];
    const void* b1 = d_in[19];
    const void* W2 = d_in[20];
    const void* b2 = d_in[21];
    const void* W3 = d_in[22];
    const void* b3 = d_in[23];

    const int E = in_sizes[0] / 64;      // 100000
    const int M = in_sizes[2];           // 300000
    const int eb   = (E + 63) / 64;      // k_pq / k_gru blocks
    const int nsp  = (M + 63) / 64;      // 64-pair spans
    const int scb  = (nsp + 3) / 4;      // k_scat blocks (4 waves each)
    const int NR   = 2 * nsp;            // boundary records
    const int fixb = (NR * 64 + 255) / 256;

    // ---- workspace layout (~68 MB) ----
    ushort* B1   = (ushort*)d_ws;                  // bf16 link state [E*64]
    ushort* B2   = B1 + (size_t)E * 64;            // bf16 node state [E*64]
    ushort* agg  = B2 + (size_t)E * 64;            // bf16 agg (shared) [E*64]
    ushort* PQ   = agg + (size_t)E * 64;           // bf16 [E*128] (shared per phase)
    int*    fiS  = (int*)(PQ + (size_t)E * 128);   // sorted first [M]
    int*    seS  = fiS + M;                        // sorted second [M]
    ushort* bndVal = (ushort*)(seS + M);           // [NR*64]
    int*    bndDst = (int*)(bndVal + (size_t)NR * 64);
    short*  sb   = (short*)(bndDst + NR);
    size_t so = 0;
    short* Wpq_e = sb + so; so += 8192;
    short* Wpq_n = sb + so; so += 8192;
    short* Gxb_e = sb + so; so += 12288;
    short* Ghb_e = sb + so; so += 12288;
    short* Gxb_n = sb + so; so += 12288;
    short* Ghb_n = sb + so; so += 12288;
    float* fb = (float*)(sb + so);
    size_t fo = 0;
    float* bm_e  = fb + fo; fo += 64;
    float* bm_n  = fb + fo; fo += 64;
    float* bgx_e = fb + fo; fo += 192;
    float* bgh_e = fb + fo; fo += 192;
    float* bgx_n = fb + fo; fo += 192;
    float* bgh_n = fb + fo; fo += 192;
    int* dflag = (int*)(fb + fo);
    // overlays: sort scratch in agg; pooledR in PQ; pooled/h1/h2 in fiS/seS
    int* cnt   = (int*)agg;
    int* bsum  = cnt + E;
    int* ebsum = bsum + 512;
    float* pooledR = (float*)PQ;        // 8.4 MB <= 25.6 MB
    float* pooled  = (float*)fiS;
    float* h1      = pooled + 32768;
    float* h2      = h1 + 65536;

    // ---- dtype + init + weight prep ----
    k_detect<<<1, 64, 0, stream>>>((const ushort*)graph_state, dflag);
    k_init_ls<<<(E * 64 + 255) / 256, 256, 0, stream>>>(graph_state, B1, E, dflag);
    k_init_ns<<<(E * 64 + 255) / 256, 256, 0, stream>>>(node_state, B2, E, dflag);
    k_prep_pqWb<<<32, 256, 0, stream>>>(Wpq_e, W_msg, 64, 64, dflag);
    k_prep_pqWb<<<32, 256, 0, stream>>>(Wpq_n, W_nmsg, DNODE, DNODE, dflag);
    k_prep_gruWb<<<48, 256, 0, stream>>>(Gxb_e, Wx_e, 64, dflag);
    k_prep_gruWb<<<48, 256, 0, stream>>>(Ghb_e, Wh_e, 64, dflag);
    k_prep_gruWb<<<48, 256, 0, stream>>>(Gxb_n, Wx_n, DNODE, dflag);
    k_prep_gruWb<<<48, 256, 0, stream>>>(Ghb_n, Wh_n, DNODE, dflag);
    k_prep_padvec<<<1, 256, 0, stream>>>(bm_e, b_msg, 64, 64, dflag);
    k_prep_padvec<<<1, 256, 0, stream>>>(bm_n, b_nmsg, DNODE, 64, dflag);
    k_prep_grub<<<1, 256, 0, stream>>>(bgx_e, bx_e, 64, dflag);
    k_prep_grub<<<1, 256, 0, stream>>>(bgh_e, bh_e, 64, dflag);
    k_prep_grub<<<1, 256, 0, stream>>>(bgx_n, bx_n, DNODE, dflag);
    k_prep_grub<<<1, 256, 0, stream>>>(bgh_n, bh_n, DNODE, dflag);

    // ---- counting sort by `second` -> fiS/seS (scratch overlays agg) ----
    const int NB = (E + 255) / 256;
    hipMemsetAsync(cnt, 0, (size_t)E * sizeof(int), stream);
    k_hist<<<(M + 255) / 256, 256, 0, stream>>>(second, cnt, M);
    k_scan_block<<<NB, 256, 0, stream>>>(cnt, bsum, E);
    k_scan_top<<<1, 64, 0, stream>>>(bsum, ebsum, NB);
    k_scan_add<<<NB, 256, 0, stream>>>(cnt, ebsum, E);
    k_scatter<<<(M + 255) / 256, 256, 0, stream>>>(first, second, cnt, fiS, seS, M);

    // ---- message passing: per iteration, link phase then node phase ----
    for (int it = 0; it < 4; ++it) {
        // link
        k_pq  <<<eb, 256, 0, stream>>>(B1, Wpq_e, PQ, agg, E);
        k_scat<<<scb, 256, 0, stream>>>(PQ, fiS, seS, bm_e, agg, bndVal, bndDst, M);
        k_fix <<<fixb, 256, 0, stream>>>(bndDst, bndVal, agg, NR);
        k_gru <<<eb, 256, 0, stream>>>(agg, B1, Gxb_e, Ghb_e, bgx_e, bgh_e, E);
        // node
        k_pq  <<<eb, 256, 0, stream>>>(B2, Wpq_n, PQ, agg, E);
        k_scat<<<scb, 256, 0, stream>>>(PQ, fiS, seS, bm_n, agg, bndVal, bndDst, M);
        k_fix <<<fixb, 256, 0, stream>>>(bndDst, bndVal, agg, NR);
        k_gru <<<eb, 256, 0, stream>>>(agg, B2, Gxb_n, Ghb_n, bgx_n, bgh_n, E);
    }

    // ---- readout ----
    hipMemsetAsync(pooledR, 0, (size_t)64 * NGRAPH * 128 * sizeof(float), stream);
    k_pool<<<(int)(((ll)E * 128 + 255) / 256), 256, 0, stream>>>(B1, B2, gid, pooledR, E);
    k_pool_red<<<(NGRAPH * 128) / 256, 256, 0, stream>>>(pooledR, pooled);
    k_mlp1<<<256, 256, 0, stream>>>(pooled, W1, b1, h1, dflag);
    k_mlp2<<<256, 256, 0, stream>>>(h1, W2, b2, h2, dflag);
    k_mlp3<<<1, 256, 0, stream>>>(h2, W3, b3, d_out, dflag);
}

// Round 10
// 910.302 us; speedup vs baseline: 4.3114x; 1.1676x over previous
//
#include <hip/hip_runtime.h>
#include <hip/hip_bf16.h>

#define DNODE 59
#define NGRAPH 256
typedef __hip_bfloat16 bf16;
typedef long long ll;
typedef unsigned short ushort;
typedef short short8v __attribute__((ext_vector_type(8)));
typedef float float4v __attribute__((ext_vector_type(4)));

__device__ __forceinline__ float b2f(bf16 x) { return __bfloat162float(x); }
__device__ __forceinline__ float bs2f(ushort u) {
    return __uint_as_float(((unsigned int)u) << 16);
}
__device__ __forceinline__ float ldv(const void* p, ll i, int isf) {
    return isf ? ((const float*)p)[i] : b2f(((const bf16*)p)[i]);
}
__device__ __forceinline__ ushort f2bs(float x) {   // RNE
    unsigned int u = __float_as_uint(x);
    u += 0x7fffu + ((u >> 16) & 1u);
    return (ushort)(u >> 16);
}
__device__ __forceinline__ float frcp(float x) { return __builtin_amdgcn_rcpf(x); }
__device__ __forceinline__ float selu_f(float x) {
    const float scale = 1.0507009873554805f;
    const float alpha = 1.6732632423543772f;
    return x > 0.f ? scale * x : scale * alpha * (__expf(x) - 1.f);
}
__device__ __forceinline__ float fsigmoid(float x) { return frcp(1.f + __expf(-x)); }
__device__ __forceinline__ float ftanh(float x) {
    float t = __expf(-2.f * fabsf(x));
    return copysignf((1.f - t) * frcp(1.f + t), x);
}

// ---------------- dtype detector (bf16 vs fp32 tensors) --------------------------
__global__ void k_detect(const ushort* __restrict__ gsu, int* __restrict__ flag)
{
    if (threadIdx.x == 0 && blockIdx.x == 0) {
        int wild = 0;
        for (int i = 0; i < 512; ++i) {
            int e = (gsu[i] >> 7) & 0xFF;
            if (e >= 0x8F) wild++;
        }
        *flag = (wild >= 20) ? 1 : 0;
    }
}

// ---------------- fused init + weight prep (one launch) --------------------------
__global__ void k_prep_all(const void* __restrict__ gs, const void* __restrict__ nsb,
                           ushort* __restrict__ B1, ushort* __restrict__ B2,
                           const void* W_msg, const void* W_nmsg,
                           const void* Wx_e, const void* Wh_e,
                           const void* Wx_n, const void* Wh_n,
                           const void* b_msg, const void* b_nmsg,
                           const void* bx_e, const void* bh_e,
                           const void* bx_n, const void* bh_n,
                           short* Wpq_e, short* Wpq_n,
                           short* Gxb_e, short* Ghb_e, short* Gxb_n, short* Ghb_n,
                           float* bm_e, float* bm_n,
                           float* bgx_e, float* bgh_e, float* bgx_n, float* bgh_n,
                           int E, const int* __restrict__ dflag)
{
    const int isf = *dflag;
    int b = blockIdx.x, t = threadIdx.x;
    const int ebi = (E * 64 + 255) / 256;

    if (b < ebi) {                      // link state init
        int i = b * 256 + t;
        if (i < E * 64) B1[i] = f2bs(ldv(gs, i, isf));
        return;
    }
    b -= ebi;
    if (b < ebi) {                      // node state init (padded to 64)
        int i = b * 256 + t;
        if (i < E * 64) {
            int e = i >> 6, c = i & 63;
            B2[i] = (c < DNODE) ? f2bs(ldv(nsb, (ll)e * DNODE + c, isf)) : 0;
        }
        return;
    }
    b -= ebi;
    if (b < 64) {                       // msg PQ weights: [8 kb][128 cols][8]
        const void* src = (b < 32) ? W_msg : W_nmsg;
        short* dst = (b < 32) ? Wpq_e : Wpq_n;
        int KH = (b < 32) ? 64 : DNODE;
        int i = (b & 31) * 256 + t;     // 0..8191
        int k = i >> 7, j = i & 127, half = j >> 6, c = j & 63;
        float v = 0.f;
        if (k < KH && c < KH) v = ldv(src, (ll)(half * KH + k) * KH + c, isf);
        dst[(k >> 3) * 1024 + j * 8 + (k & 7)] = (short)f2bs(v);
        return;
    }
    b -= 64;
    if (b < 192) {                      // GRU weights: [8 kb][192 cols][8]
        int w = b / 48, lb = b % 48;
        const void* src = (w == 0) ? Wx_e : (w == 1) ? Wh_e : (w == 2) ? Wx_n : Wh_n;
        short* dst = (w == 0) ? Gxb_e : (w == 1) ? Ghb_e : (w == 2) ? Gxb_n : Ghb_n;
        int D = (w < 2) ? 64 : DNODE;
        int i = lb * 256 + t;
        if (i >= 64 * 192) return;
        int k = i / 192, c = i % 192, g = c >> 6, d = c & 63;
        float v = 0.f;
        if (k < D && d < D) v = ldv(src, (ll)k * 3 * D + g * D + d, isf);
        dst[(k >> 3) * 1536 + c * 8 + (k & 7)] = (short)f2bs(v);
        return;
    }
    // biases (one block)
    for (int i = t; i < 896; i += 256) {
        if (i < 64)        bm_e[i] = ldv(b_msg, i, isf);
        else if (i < 128)  { int c = i - 64;  bm_n[c]  = (c < DNODE) ? ldv(b_nmsg, c, isf) : 0.f; }
        else if (i < 320)  { int c = i - 128; bgx_e[c] = ldv(bx_e, c, isf); }
        else if (i < 512)  { int c = i - 320; bgh_e[c] = ldv(bh_e, c, isf); }
        else if (i < 704)  { int c = i - 512; int g = c >> 6, d = c & 63;
                             bgx_n[c] = (d < DNODE) ? ldv(bx_n, (ll)g * DNODE + d, isf) : 0.f; }
        else               { int c = i - 704; int g = c >> 6, d = c & 63;
                             bgh_n[c] = (d < DNODE) ? ldv(bh_n, (ll)g * DNODE + d, isf) : 0.f; }
    }
}

// ---------------- counting sort of pairs by `second` ------------------------------
__global__ void k_hist(const int* __restrict__ second, int* __restrict__ cnt, int M)
{
    int m = blockIdx.x * 256 + threadIdx.x;
    if (m < M) atomicAdd(&cnt[second[m]], 1);
}
__global__ void k_scan_block(int* __restrict__ cnt, int* __restrict__ bsum, int E)
{
    __shared__ int s[256];
    int t = threadIdx.x, i = blockIdx.x * 256 + t;
    int v = (i < E) ? cnt[i] : 0;
    s[t] = v;
    __syncthreads();
    #pragma unroll
    for (int d = 1; d < 256; d <<= 1) {
        int xv = (t >= d) ? s[t - d] : 0;
        __syncthreads();
        s[t] += xv;
        __syncthreads();
    }
    if (i < E) cnt[i] = s[t] - v;
    if (t == 255) bsum[blockIdx.x] = s[255];
}
__global__ void k_scan_top(const int* __restrict__ bsum, int* __restrict__ ebsum, int NB)
{
    if (threadIdx.x == 0 && blockIdx.x == 0) {
        int run = 0;
        for (int b = 0; b < NB; ++b) { ebsum[b] = run; run += bsum[b]; }
    }
}
__global__ void k_scan_add(int* __restrict__ cnt, const int* __restrict__ ebsum, int E)
{
    int i = blockIdx.x * 256 + threadIdx.x;
    if (i < E) cnt[i] += ebsum[blockIdx.x];
}
__global__ void k_scatter(const int* __restrict__ first, const int* __restrict__ second,
                          int* __restrict__ cnt, int* __restrict__ fiS,
                          int* __restrict__ seS, int M)
{
    int m = blockIdx.x * 256 + threadIdx.x;
    if (m < M) {
        int s = second[m];
        int pos = atomicAdd(&cnt[s], 1);
        fiS[pos] = first[m];
        seS[pos] = second[m];
    }
}

// ---------------- dense PQ GEMM: PQ[e] = B[e] @ [W_top | W_bot], also zero agg ----
__launch_bounds__(256)
__global__ void k_pq(const ushort* __restrict__ B, const short* __restrict__ Wb,
                     ushort* __restrict__ PQ, ushort* __restrict__ aggz, int E)
{
    __shared__ __align__(16) short Ms16[64 * 136];   // 17,408 B relay
    const int t = threadIdx.x;
    const int e0 = blockIdx.x * 64;
    const int lane = t & 63, wv = t >> 6, quad = lane >> 4, l16 = lane & 15;
    const int em = wv * 16;

    int er = e0 + em + l16; if (er >= E) er = E - 1;

    float4v acc[8];
    #pragma unroll
    for (int i = 0; i < 8; ++i) acc[i] = (float4v){0.f, 0.f, 0.f, 0.f};

    #pragma unroll
    for (int c = 0; c < 2; ++c) {
        int kb = c * 4 + quad;
        short8v a = *(const short8v*)&B[(ll)er * 64 + kb * 8];
        #pragma unroll
        for (int tn = 0; tn < 8; ++tn) {
            short8v bw = *(const short8v*)&Wb[(kb * 128 + tn * 16 + l16) * 8];
            acc[tn] = __builtin_amdgcn_mfma_f32_16x16x32_bf16(a, bw, acc[tn], 0, 0, 0);
        }
    }

    // zero agg rows for this block
    #pragma unroll
    for (int r = 0; r < 2; ++r) {
        int id = t + r * 256;
        int row = id >> 3, q = id & 7;
        if (e0 + row < E)
            *(uint4*)&aggz[(ll)(e0 + row) * 64 + q * 8] = make_uint4(0u, 0u, 0u, 0u);
    }

    // relay acc -> bf16 LDS -> coalesced PQ store
    #pragma unroll
    for (int tn = 0; tn < 8; ++tn)
        #pragma unroll
        for (int r = 0; r < 4; ++r)
            Ms16[(em + quad * 4 + r) * 136 + tn * 16 + l16] = (short)f2bs(acc[tn][r]);
    __syncthreads();
    #pragma unroll
    for (int r = 0; r < 4; ++r) {
        int id = t + r * 256;
        int row = id >> 4, q = id & 15;
        if (e0 + row < E)
            *(uint4*)&PQ[(ll)(e0 + row) * 128 + q * 8] = *(uint4*)&Ms16[row * 136 + q * 8];
    }
}

// ---------------- scatter-agg over sorted runs: one wave per 64-pair span ---------
// 4-deep P/Q prefetch rings -> 8 outstanding loads, no dependent run-head stall.
__launch_bounds__(256)
__global__ void k_scat(const ushort* __restrict__ PQ,
                       const int* __restrict__ fiS, const int* __restrict__ seS,
                       const float* __restrict__ bm,
                       ushort* __restrict__ aggb,
                       ushort* __restrict__ bndVal, int* __restrict__ bndDst,
                       int M)
{
    const int lane = threadIdx.x & 63, wv = threadIdx.x >> 6;
    const int sp = blockIdx.x * 4 + wv;
    const int m0 = sp * 64;
    const float bb = bm[lane];

    int mm = m0 + lane;
    int fiv = (mm < M) ? fiS[mm] : 0;
    int sev = (mm < M) ? seS[mm] : -1;

    int cur = __shfl(sev, 0);
    if (cur < 0) {
        if (lane == 0) { bndDst[2 * sp] = -1; bndDst[2 * sp + 1] = -1; }
        return;
    }

    float pv[4], qv[4];
    #pragma unroll
    for (int u = 0; u < 4; ++u) {
        int f = __shfl(fiv, u), s = __shfl(sev, u);
        if (s < 0) s = 0;
        pv[u] = bs2f(PQ[(ll)f * 128 + lane]);
        qv[u] = bs2f(PQ[(ll)s * 128 + 64 + lane]);
    }

    float sum = 0.f;
    bool headDone = false;
    for (int i0 = 0; i0 < 64; i0 += 4) {
        #pragma unroll
        for (int u = 0; u < 4; ++u) {
            int i = i0 + u;
            int sv = __shfl(sev, i);
            float pcur = pv[u], qcur = qv[u];
            int i4 = i + 4;
            if (i4 < 64) {              // prefetch ring refill
                int fn = __shfl(fiv, i4), sn = __shfl(sev, i4);
                if (sn < 0) sn = 0;
                pv[u] = bs2f(PQ[(ll)fn * 128 + lane]);
                qv[u] = bs2f(PQ[(ll)sn * 128 + 64 + lane]);
            }
            if (sv >= 0) {
                if (sv != cur) {
                    if (!headDone) {
                        bndVal[(ll)(2 * sp) * 64 + lane] = f2bs(sum);
                        if (lane == 0) bndDst[2 * sp] = cur;
                        headDone = true;
                    } else {
                        aggb[(ll)cur * 64 + lane] = f2bs(sum);
                    }
                    cur = sv; sum = 0.f;
                }
                sum += selu_f(pcur + qcur + bb);
            }
        }
    }
    if (!headDone) {
        bndVal[(ll)(2 * sp) * 64 + lane] = f2bs(sum);
        if (lane == 0) { bndDst[2 * sp] = cur; bndDst[2 * sp + 1] = -1; }
    } else {
        bndVal[(ll)(2 * sp + 1) * 64 + lane] = f2bs(sum);
        if (lane == 0) bndDst[2 * sp + 1] = cur;
    }
}

// ---------------- boundary fixup: merge chained records per destination ----------
__global__ void k_fix(const int* __restrict__ bndDst, const ushort* __restrict__ bndVal,
                      ushort* __restrict__ aggb, int NR)
{
    int idx = (blockIdx.x * 256 + threadIdx.x) >> 6;
    int lane = threadIdx.x & 63;
    if (idx >= NR) return;
    int dst = bndDst[idx];
    if (dst < 0) return;
    int pprev = idx - 1;
    while (pprev >= 0 && bndDst[pprev] < 0) --pprev;
    if (pprev >= 0 && bndDst[pprev] == dst) return;    // not chain head
    float s = 0.f;
    for (int r = idx; r < NR; ++r) {
        int d = bndDst[r];
        if (d == dst) s += bs2f(bndVal[(ll)r * 64 + lane]);
        else if (d >= 0) break;
    }
    aggb[(ll)dst * 64 + lane] = f2bs(s);
}

// ---------------- GRU: joint z/r accumulators, fast rcp gates --------------------
__launch_bounds__(256)
__global__ void k_gru(const ushort* __restrict__ xb, ushort* __restrict__ hb,
                      const short* __restrict__ Gxb, const short* __restrict__ Ghb,
                      const float* __restrict__ bgx, const float* __restrict__ bgh,
                      int E)
{
    const int t = threadIdx.x;
    const int e0 = blockIdx.x * 64;
    const int lane = t & 63, wv = t >> 6, quad = lane >> 4, l16 = lane & 15;
    const int em = wv * 16;
    int er = e0 + em + l16; if (er >= E) er = E - 1;

    float4v zr[8], xh[4], hh[4];
    #pragma unroll
    for (int i = 0; i < 8; ++i) zr[i] = (float4v){0.f, 0.f, 0.f, 0.f};
    #pragma unroll
    for (int i = 0; i < 4; ++i) { xh[i] = (float4v){0.f,0.f,0.f,0.f}; hh[i] = (float4v){0.f,0.f,0.f,0.f}; }

    #pragma unroll
    for (int c = 0; c < 2; ++c) {
        int kb = c * 4 + quad;
        short8v a_x = *(const short8v*)&xb[(ll)er * 64 + kb * 8];
        short8v a_h = *(const short8v*)&hb[(ll)er * 64 + kb * 8];
        #pragma unroll
        for (int tn = 0; tn < 8; ++tn) {    // z,r gates: x and h into one acc
            short8v b_x = *(const short8v*)&Gxb[(kb * 192 + tn * 16 + l16) * 8];
            zr[tn] = __builtin_amdgcn_mfma_f32_16x16x32_bf16(a_x, b_x, zr[tn], 0, 0, 0);
            short8v b_h = *(const short8v*)&Ghb[(kb * 192 + tn * 16 + l16) * 8];
            zr[tn] = __builtin_amdgcn_mfma_f32_16x16x32_bf16(a_h, b_h, zr[tn], 0, 0, 0);
        }
        #pragma unroll
        for (int tn = 0; tn < 4; ++tn) {    // hh gate: keep x and h separate
            short8v b_x = *(const short8v*)&Gxb[(kb * 192 + (8 + tn) * 16 + l16) * 8];
            xh[tn] = __builtin_amdgcn_mfma_f32_16x16x32_bf16(a_x, b_x, xh[tn], 0, 0, 0);
            short8v b_h = *(const short8v*)&Ghb[(kb * 192 + (8 + tn) * 16 + l16) * 8];
            hh[tn] = __builtin_amdgcn_mfma_f32_16x16x32_bf16(a_h, b_h, hh[tn], 0, 0, 0);
        }
    }

    // hoisted biases
    float bz[4], br_[4], bxh[4], bhh[4];
    #pragma unroll
    for (int j = 0; j < 4; ++j) {
        int d = j * 16 + l16;
        bz[j]  = bgx[d] + bgh[d];
        br_[j] = bgx[64 + d] + bgh[64 + d];
        bxh[j] = bgx[128 + d];
        bhh[j] = bgh[128 + d];
    }

    #pragma unroll
    for (int r = 0; r < 4; ++r) {
        int e = e0 + em + quad * 4 + r;
        if (e >= E) continue;
        #pragma unroll
        for (int j = 0; j < 4; ++j) {
            int d = j * 16 + l16;
            float z  = fsigmoid(zr[j][r] + bz[j]);
            float rr = fsigmoid(zr[4 + j][r] + br_[j]);
            float cc = ftanh(xh[j][r] + bxh[j] + rr * (hh[j][r] + bhh[j]));
            float ho = bs2f(hb[(ll)e * 64 + d]);
            hb[(ll)e * 64 + d] = f2bs(z * ho + (1.f - z) * cc);
        }
    }
}

// ---------------- readout pool (64-way replicated atomics) -----------------------
__global__ void k_pool(const ushort* __restrict__ lsb, const ushort* __restrict__ nsb,
                       const int* __restrict__ gid, float* __restrict__ pooledR, int E)
{
    ll i = (ll)blockIdx.x * 256 + threadIdx.x;
    if (i >= (ll)E * 128) return;
    int e = (int)(i >> 7), c = (int)(i & 127);
    if (c >= 64 + DNODE) return;
    int g = gid[e];
    int rep = blockIdx.x & 63;
    float v = (c < 64) ? bs2f(lsb[(ll)e * 64 + c]) : bs2f(nsb[(ll)e * 64 + (c - 64)]);
    atomicAdd(&pooledR[((ll)rep * NGRAPH + g) * 128 + c], v);
}
__global__ void k_pool_red(const float* __restrict__ pooledR, float* __restrict__ pooled)
{
    int i = blockIdx.x * 256 + threadIdx.x;
    float s = 0.f;
    for (int r = 0; r < 64; ++r) s += pooledR[(ll)r * NGRAPH * 128 + i];
    pooled[i] = s;
}

// ---------------- readout MLP ----------------------------------------------------
__global__ void k_mlp1(const float* __restrict__ pooled, const void* __restrict__ W1,
                       const void* __restrict__ b1, float* __restrict__ h1,
                       const int* __restrict__ dflag)
{
    int isf = *dflag;
    int g = blockIdx.x, j = threadIdx.x;
    float acc = ldv(b1, j, isf);
    for (int k = 0; k < 64 + DNODE; k++)
        acc = fmaf(pooled[g * 128 + k], ldv(W1, (ll)k * 256 + j, isf), acc);
    h1[g * 256 + j] = selu_f(acc);
}
__global__ void k_mlp2(const float* __restrict__ h1, const void* __restrict__ W2,
                       const void* __restrict__ b2, float* __restrict__ h2,
                       const int* __restrict__ dflag)
{
    int isf = *dflag;
    int g = blockIdx.x, j = threadIdx.x;
    float acc = ldv(b2, j, isf);
    for (int k = 0; k < 256; k++)
        acc = fmaf(h1[g * 256 + k], ldv(W2, (ll)k * 256 + j, isf), acc);
    h2[g * 256 + j] = selu_f(acc);
}
__global__ void k_mlp3(const float* __restrict__ h2, const void* __restrict__ W3,
                       const void* __restrict__ b3, void* __restrict__ out,
                       const int* __restrict__ dflag)
{
    int isf = *dflag;
    int g = threadIdx.x;
    float acc = ldv(b3, 0, isf);
    for (int k = 0; k < 256; k++)
        acc = fmaf(h2[g * 256 + k], ldv(W3, k, isf), acc);
    if (isf) ((float*)out)[g] = acc;
    else     ((bf16*)out)[g] = __float2bfloat16(acc);
}

extern "C" void kernel_launch(void* const* d_in, const int* in_sizes, int n_in,
                              void* d_out, int out_size, void* d_ws, size_t ws_size,
                              hipStream_t stream)
{
    const void* graph_state = d_in[0];
    const void* node_state  = d_in[1];
    const int*  first   = (const int*)d_in[2];
    const int*  second  = (const int*)d_in[3];
    const int*  gid     = (const int*)d_in[4];
    const void* W_msg  = d_in[6];
    const void* b_msg  = d_in[7];
    const void* Wx_e   = d_in[8];
    const void* Wh_e   = d_in[9];
    const void* bx_e   = d_in[10];
    const void* bh_e   = d_in[11];
    const void* W_nmsg = d_in[12];
    const void* b_nmsg = d_in[13];
    const void* Wx_n   = d_in[14];
    const void* Wh_n   = d_in[15];
    const void* bx_n   = d_in[16];
    const void* bh_n   = d_in[17];
    const void* W1 = d_in[18];
    const void* b1 = d_in[19];
    const void* W2 = d_in[20];
    const void* b2 = d_in[21];
    const void* W3 = d_in[22];
    const void* b3 = d_in[23];

    const int E = in_sizes[0] / 64;      // 100000
    const int M = in_sizes[2];           // 300000
    const int eb   = (E + 63) / 64;      // k_pq / k_gru blocks
    const int nsp  = (M + 63) / 64;      // 64-pair spans
    const int scb  = (nsp + 3) / 4;      // k_scat blocks (4 waves each)
    const int NR   = 2 * nsp;            // boundary records
    const int fixb = (NR * 64 + 255) / 256;

    // ---- workspace layout (~68 MB) ----
    ushort* B1   = (ushort*)d_ws;                  // bf16 link state [E*64]
    ushort* B2   = B1 + (size_t)E * 64;            // bf16 node state [E*64]
    ushort* agg  = B2 + (size_t)E * 64;            // bf16 agg (shared) [E*64]
    ushort* PQ   = agg + (size_t)E * 64;           // bf16 [E*128] (shared per phase)
    int*    fiS  = (int*)(PQ + (size_t)E * 128);   // sorted first [M]
    int*    seS  = fiS + M;                        // sorted second [M]
    ushort* bndVal = (ushort*)(seS + M);           // [NR*64]
    int*    bndDst = (int*)(bndVal + (size_t)NR * 64);
    short*  sb   = (short*)(bndDst + NR);
    size_t so = 0;
    short* Wpq_e = sb + so; so += 8192;
    short* Wpq_n = sb + so; so += 8192;
    short* Gxb_e = sb + so; so += 12288;
    short* Ghb_e = sb + so; so += 12288;
    short* Gxb_n = sb + so; so += 12288;
    short* Ghb_n = sb + so; so += 12288;
    float* fb = (float*)(sb + so);
    size_t fo = 0;
    float* bm_e  = fb + fo; fo += 64;
    float* bm_n  = fb + fo; fo += 64;
    float* bgx_e = fb + fo; fo += 192;
    float* bgh_e = fb + fo; fo += 192;
    float* bgx_n = fb + fo; fo += 192;
    float* bgh_n = fb + fo; fo += 192;
    int* dflag = (int*)(fb + fo);
    // overlays: sort scratch in agg; pooledR in PQ; pooled/h1/h2 in fiS/seS
    int* cnt   = (int*)agg;
    int* bsum  = cnt + E;
    int* ebsum = bsum + 512;
    float* pooledR = (float*)PQ;        // 8.4 MB <= 25.6 MB
    float* pooled  = (float*)fiS;
    float* h1      = pooled + 32768;
    float* h2      = h1 + 65536;

    // ---- dtype + fused init/prep ----
    k_detect<<<1, 64, 0, stream>>>((const ushort*)graph_state, dflag);
    const int ebi = (E * 64 + 255) / 256;
    k_prep_all<<<2 * ebi + 64 + 192 + 1, 256, 0, stream>>>(
        graph_state, node_state, B1, B2,
        W_msg, W_nmsg, Wx_e, Wh_e, Wx_n, Wh_n,
        b_msg, b_nmsg, bx_e, bh_e, bx_n, bh_n,
        Wpq_e, Wpq_n, Gxb_e, Ghb_e, Gxb_n, Ghb_n,
        bm_e, bm_n, bgx_e, bgh_e, bgx_n, bgh_n, E, dflag);

    // ---- counting sort by `second` -> fiS/seS (scratch overlays agg) ----
    const int NB = (E + 255) / 256;
    hipMemsetAsync(cnt, 0, (size_t)E * sizeof(int), stream);
    k_hist<<<(M + 255) / 256, 256, 0, stream>>>(second, cnt, M);
    k_scan_block<<<NB, 256, 0, stream>>>(cnt, bsum, E);
    k_scan_top<<<1, 64, 0, stream>>>(bsum, ebsum, NB);
    k_scan_add<<<NB, 256, 0, stream>>>(cnt, ebsum, E);
    k_scatter<<<(M + 255) / 256, 256, 0, stream>>>(first, second, cnt, fiS, seS, M);

    // ---- message passing: per iteration, link phase then node phase ----
    for (int it = 0; it < 4; ++it) {
        // link
        k_pq  <<<eb, 256, 0, stream>>>(B1, Wpq_e, PQ, agg, E);
        k_scat<<<scb, 256, 0, stream>>>(PQ, fiS, seS, bm_e, agg, bndVal, bndDst, M);
        k_fix <<<fixb, 256, 0, stream>>>(bndDst, bndVal, agg, NR);
        k_gru <<<eb, 256, 0, stream>>>(agg, B1, Gxb_e, Ghb_e, bgx_e, bgh_e, E);
        // node
        k_pq  <<<eb, 256, 0, stream>>>(B2, Wpq_n, PQ, agg, E);
        k_scat<<<scb, 256, 0, stream>>>(PQ, fiS, seS, bm_n, agg, bndVal, bndDst, M);
        k_fix <<<fixb, 256, 0, stream>>>(bndDst, bndVal, agg, NR);
        k_gru <<<eb, 256, 0, stream>>>(agg, B2, Gxb_n, Ghb_n, bgx_n, bgh_n, E);
    }

    // ---- readout ----
    hipMemsetAsync(pooledR, 0, (size_t)64 * NGRAPH * 128 * sizeof(float), stream);
    k_pool<<<(int)(((ll)E * 128 + 255) / 256), 256, 0, stream>>>(B1, B2, gid, pooledR, E);
    k_pool_red<<<(NGRAPH * 128) / 256, 256, 0, stream>>>(pooledR, pooled);
    k_mlp1<<<256, 256, 0, stream>>>(pooled, W1, b1, h1, dflag);
    k_mlp2<<<256, 256, 0, stream>>>(h1, W2, b2, h2, dflag);
    k_mlp3<<<1, 256, 0, stream>>>(h2, W3, b3, d_out, dflag);
}